// Round 1
// baseline (1278.221 us; speedup 1.0000x reference)
//
#include <hip/hip_runtime.h>
#include <hip/hip_bf16.h>
#include <math.h>

#define S_ 3
#define B_ 4
#define C_ 256
#define H_ 64
#define W_ 64
#define HW_ 4096
#define CHW_ (C_*HW_)
#define NH_ 8
#define HD_ 32
#define EPS_ 1e-5f

static constexpr size_t SLOT      = (size_t)S_ * B_ * CHW_;      // 12,582,912 floats
static constexpr size_t OFF_SLOT0 = 0;
static constexpr size_t OFF_SLOT1 = SLOT;
static constexpr size_t OFF_SLOT2 = 2 * SLOT;
static constexpr size_t OFF_AW    = 3 * SLOT;                    // B*NH*3*HW = 393,216
static constexpr size_t OFF_POOL  = OFF_AW + (size_t)B_*NH_*3*HW_;
static constexpr size_t OFF_H     = OFF_POOL + B_*S_*C_;         // 3072
static constexpr size_t OFF_WSM   = OFF_H + B_*C_;               // 1024

__device__ __forceinline__ float gelu_exact(float x) {
    return 0.5f * x * (1.0f + erff(x * 0.70710678118654752440f));
}

// ---------------------------------------------------------------------------
// pooled[b, s*C + c] = mean over hw of x[s,b,c,:,:]
__global__ __launch_bounds__(256)
void pool_mean(const float* __restrict__ x, float* __restrict__ pooled) {
    const int blk = blockIdx.x;             // (s*B + b)*C + c
    const int c  = blk & (C_-1);
    const int sb = blk >> 8;
    const int s  = sb >> 2, b = sb & 3;
    const float* p = x + (size_t)blk * HW_;
    float sum = 0.f;
    for (int i = threadIdx.x; i < HW_; i += 256) sum += p[i];
    #pragma unroll
    for (int off = 32; off; off >>= 1) sum += __shfl_down(sum, off);
    __shared__ float red[4];
    if ((threadIdx.x & 63) == 0) red[threadIdx.x >> 6] = sum;
    __syncthreads();
    if (threadIdx.x == 0) {
        float t = red[0] + red[1] + red[2] + red[3];
        pooled[b * (S_*C_) + s * C_ + c] = t * (1.0f / HW_);
    }
}

// h[b, o] = gelu(pooled[b,:] . w1[o,:] + b1[o]);   one block per o
__global__ __launch_bounds__(256)
void imp1(const float* __restrict__ pooled, const float* __restrict__ w1,
          const float* __restrict__ b1, float* __restrict__ h) {
    const int o = blockIdx.x;
    const int tid = threadIdx.x;
    float part[4] = {0.f, 0.f, 0.f, 0.f};
    for (int j = tid; j < S_*C_; j += 256) {
        const float wv = w1[o * (S_*C_) + j];
        #pragma unroll
        for (int b = 0; b < 4; ++b) part[b] = fmaf(pooled[b*(S_*C_) + j], wv, part[b]);
    }
    #pragma unroll
    for (int off = 32; off; off >>= 1)
        #pragma unroll
        for (int b = 0; b < 4; ++b) part[b] += __shfl_down(part[b], off);
    __shared__ float red[4][4];
    if ((tid & 63) == 0) {
        #pragma unroll
        for (int b = 0; b < 4; ++b) red[tid >> 6][b] = part[b];
    }
    __syncthreads();
    if (tid < 4) {
        float t = red[0][tid] + red[1][tid] + red[2][tid] + red[3][tid];
        h[tid * C_ + o] = gelu_exact(t + b1[o]);
    }
}

// w[b, s] = softmax_s(h[b,:] . w2[s,:] + b2[s])
__global__ __launch_bounds__(256)
void imp2(const float* __restrict__ h, const float* __restrict__ w2,
          const float* __restrict__ b2, float* __restrict__ wout) {
    __shared__ float hl[B_*C_];
    __shared__ float lg[4][3];
    const int tid = threadIdx.x;
    for (int i = tid; i < B_*C_; i += 256) hl[i] = h[i];
    __syncthreads();
    if (tid < 12) {
        const int b = tid / 3, s = tid % 3;
        float a = b2[s];
        for (int o = 0; o < C_; ++o) a = fmaf(hl[b*C_ + o], w2[s*C_ + o], a);
        lg[b][s] = a;
    }
    __syncthreads();
    if (tid < 4) {
        const float m = fmaxf(fmaxf(lg[tid][0], lg[tid][1]), lg[tid][2]);
        const float e0 = expf(lg[tid][0]-m), e1 = expf(lg[tid][1]-m), e2 = expf(lg[tid][2]-m);
        const float inv = 1.0f / (e0 + e1 + e2);
        wout[tid*3+0] = e0*inv; wout[tid*3+1] = e1*inv; wout[tid*3+2] = e2*inv;
    }
}

// ---------------------------------------------------------------------------
// Channel GEMM: Out[z][o][n] = sum_c W[o,c] * In[z][c][n]  (+ epilogue)
// MODE 0: +bias, BN, exact gelu (params indexed widx = perS ? z>>2 : 0)
// MODE 1: +bias
// MODE 2: +bias +resid[z]
template<int MODE>
__global__ __launch_bounds__(256)
void gemm_ck(const float* __restrict__ In, const float* __restrict__ Wb,
             const float* __restrict__ bias, const float* __restrict__ bnp,
             const float* __restrict__ resid, float* __restrict__ Out,
             int perS) {
    __shared__ float Wt[16][132];
    __shared__ float It[16][132];

    const int z = blockIdx.z;
    const int widx = perS ? (z >> 2) : 0;
    const float* Wm = Wb + (size_t)widx * (C_*C_);
    const float* bp = bias + (size_t)widx * C_;
    const float* in = In + (size_t)z * CHW_;
    float* out = Out + (size_t)z * CHW_;

    const int tid = threadIdx.x;
    const int tx = tid & 15;       // n group
    const int ty = tid >> 4;       // m group
    const int nBase = blockIdx.x * 128;
    const int mBase = blockIdx.y * 128;

    float acc[8][8];
    #pragma unroll
    for (int i = 0; i < 8; ++i)
        #pragma unroll
        for (int j = 0; j < 8; ++j) acc[i][j] = 0.f;

    for (int k0 = 0; k0 < C_; k0 += 16) {
        #pragma unroll
        for (int it = 0; it < 2; ++it) {              // W tile: 128 x 16, transposed
            const int idx = tid + it*256;
            const int m  = idx >> 2;
            const int c4 = (idx & 3) << 2;
            const float4 v = *(const float4*)&Wm[(size_t)(mBase+m)*C_ + k0 + c4];
            Wt[c4+0][m] = v.x; Wt[c4+1][m] = v.y; Wt[c4+2][m] = v.z; Wt[c4+3][m] = v.w;
        }
        #pragma unroll
        for (int it = 0; it < 2; ++it) {              // In tile: 16 x 128
            const int idx = tid + it*256;
            const int r  = idx >> 5;
            const int c4 = (idx & 31) << 2;
            *(float4*)&It[r][c4] = *(const float4*)&in[(size_t)(k0+r)*HW_ + nBase + c4];
        }
        __syncthreads();
        #pragma unroll
        for (int k = 0; k < 16; ++k) {
            float a[8], b[8];
            *(float4*)&a[0] = *(const float4*)&Wt[k][ty*8];
            *(float4*)&a[4] = *(const float4*)&Wt[k][ty*8+4];
            *(float4*)&b[0] = *(const float4*)&It[k][tx*8];
            *(float4*)&b[4] = *(const float4*)&It[k][tx*8+4];
            #pragma unroll
            for (int i = 0; i < 8; ++i)
                #pragma unroll
                for (int j = 0; j < 8; ++j)
                    acc[i][j] = fmaf(a[i], b[j], acc[i][j]);
        }
        __syncthreads();
    }

    #pragma unroll
    for (int i = 0; i < 8; ++i) {
        const int o = mBase + ty*8 + i;
        const float bi = bp[o];
        float mulc = 1.f, addc = bi;
        if constexpr (MODE == 0) {
            const float g  = bnp[(size_t)widx*4*C_ + o];
            const float be = bnp[(size_t)widx*4*C_ + C_   + o];
            const float mu = bnp[(size_t)widx*4*C_ + 2*C_ + o];
            const float va = bnp[(size_t)widx*4*C_ + 3*C_ + o];
            mulc = g * rsqrtf(va + EPS_);
            addc = (bi - mu) * mulc + be;
        }
        const size_t row = (size_t)o * HW_ + nBase + tx*8;
        float y[8];
        #pragma unroll
        for (int j = 0; j < 8; ++j) {
            float v = fmaf(acc[i][j], mulc, addc);
            if constexpr (MODE == 0) v = gelu_exact(v);
            y[j] = v;
        }
        if constexpr (MODE == 2) {
            const float4 q0 = *(const float4*)&resid[(size_t)z*CHW_ + row];
            const float4 q1 = *(const float4*)&resid[(size_t)z*CHW_ + row + 4];
            y[0]+=q0.x; y[1]+=q0.y; y[2]+=q0.z; y[3]+=q0.w;
            y[4]+=q1.x; y[5]+=q1.y; y[6]+=q1.z; y[7]+=q1.w;
        }
        float4 r0 = make_float4(y[0],y[1],y[2],y[3]);
        float4 r1 = make_float4(y[4],y[5],y[6],y[7]);
        *(float4*)&out[row]     = r0;
        *(float4*)&out[row + 4] = r1;
    }
}

// ---------------------------------------------------------------------------
// 3x3 SAME conv (K = 9*256) + bias + BN + gelu.  One z-slice per batch b.
__global__ __launch_bounds__(256)
void conv3_bn_gelu(const float* __restrict__ In, const float* __restrict__ Wc,
                   const float* __restrict__ bias, const float* __restrict__ bnp,
                   float* __restrict__ Out) {
    __shared__ float Wt[16][132];
    __shared__ float It[16][132];

    const int b = blockIdx.z;
    const float* in = In + (size_t)b * CHW_;
    float* out = Out + (size_t)b * CHW_;

    const int tid = threadIdx.x;
    const int tx = tid & 15;
    const int ty = tid >> 4;
    const int nBase = blockIdx.x * 128;
    const int mBase = blockIdx.y * 128;

    float acc[8][8];
    #pragma unroll
    for (int i = 0; i < 8; ++i)
        #pragma unroll
        for (int j = 0; j < 8; ++j) acc[i][j] = 0.f;

    for (int t9 = 0; t9 < 9; ++t9) {
        const int dy = t9 / 3 - 1, dx = t9 % 3 - 1;
        for (int k0 = 0; k0 < C_; k0 += 16) {
            #pragma unroll
            for (int it = 0; it < 8; ++it) {          // W: stride-9 gather
                const int idx = tid + it*256;
                const int m = idx >> 4;
                const int k = idx & 15;
                Wt[k][m] = Wc[(size_t)(mBase+m)*(C_*9) + (size_t)(k0+k)*9 + t9];
            }
            #pragma unroll
            for (int it = 0; it < 8; ++it) {          // shifted, zero-padded input
                const int idx = tid + it*256;
                const int r = idx >> 7;
                const int n = idx & 127;
                const int y  = (nBase + n) >> 6;
                const int xx = (nBase + n) & 63;
                const int sy = y + dy, sx = xx + dx;
                float v = 0.f;
                if (sy >= 0 && sy < H_ && sx >= 0 && sx < W_)
                    v = in[(size_t)(k0+r)*HW_ + sy*W_ + sx];
                It[r][n] = v;
            }
            __syncthreads();
            #pragma unroll
            for (int k = 0; k < 16; ++k) {
                float a[8], bb[8];
                *(float4*)&a[0]  = *(const float4*)&Wt[k][ty*8];
                *(float4*)&a[4]  = *(const float4*)&Wt[k][ty*8+4];
                *(float4*)&bb[0] = *(const float4*)&It[k][tx*8];
                *(float4*)&bb[4] = *(const float4*)&It[k][tx*8+4];
                #pragma unroll
                for (int i = 0; i < 8; ++i)
                    #pragma unroll
                    for (int j = 0; j < 8; ++j)
                        acc[i][j] = fmaf(a[i], bb[j], acc[i][j]);
            }
            __syncthreads();
        }
    }

    #pragma unroll
    for (int i = 0; i < 8; ++i) {
        const int o = mBase + ty*8 + i;
        const float g  = bnp[o];
        const float be = bnp[C_   + o];
        const float mu = bnp[2*C_ + o];
        const float va = bnp[3*C_ + o];
        const float mulc = g * rsqrtf(va + EPS_);
        const float addc = (bias[o] - mu) * mulc + be;
        const size_t row = (size_t)o * HW_ + nBase + tx*8;
        float y[8];
        #pragma unroll
        for (int j = 0; j < 8; ++j) y[j] = gelu_exact(fmaf(acc[i][j], mulc, addc));
        *(float4*)&out[row]     = make_float4(y[0],y[1],y[2],y[3]);
        *(float4*)&out[row + 4] = make_float4(y[4],y[5],y[6],y[7]);
    }
}

// ---------------------------------------------------------------------------
// Per-token-head: scores = qt.kt^T/sqrt(HD); softmax over t;
// aw[b,h,t,hw] = sum_s w[b,s]*attn[s,t]
__global__ __launch_bounds__(256)
void attn_scores(const float* __restrict__ QT, const float* __restrict__ KT,
                 const float* __restrict__ wsm, float* __restrict__ AW) {
    const int gid = blockIdx.x * 256 + threadIdx.x;
    const int b  = gid >> 12;
    const int hw = gid & (HW_-1);
    const float w0 = wsm[b*3+0], w1 = wsm[b*3+1], w2 = wsm[b*3+2];
    const size_t sStride = (size_t)B_ * CHW_;
    for (int h = 0; h < NH_; ++h) {
        const size_t base = ((size_t)b*C_ + h*HD_)*HW_ + hw;
        float s00=0,s01=0,s02=0,s10=0,s11=0,s12=0,s20=0,s21=0,s22=0;
        #pragma unroll 8
        for (int d = 0; d < HD_; ++d) {
            const size_t off = base + (size_t)d*HW_;
            const float q0 = QT[off], q1 = QT[off+sStride], q2 = QT[off+2*sStride];
            const float k0 = KT[off], k1 = KT[off+sStride], k2 = KT[off+2*sStride];
            s00 = fmaf(q0,k0,s00); s01 = fmaf(q0,k1,s01); s02 = fmaf(q0,k2,s02);
            s10 = fmaf(q1,k0,s10); s11 = fmaf(q1,k1,s11); s12 = fmaf(q1,k2,s12);
            s20 = fmaf(q2,k0,s20); s21 = fmaf(q2,k1,s21); s22 = fmaf(q2,k2,s22);
        }
        const float scl = 0.17677669529663687f;   // 1/sqrt(32)
        float aw0[3], aw1[3], aw2[3];
        {
            float m = fmaxf(fmaxf(s00,s01),s02);
            float e0 = expf(s00*scl - m*scl), e1 = expf(s01*scl - m*scl), e2 = expf(s02*scl - m*scl);
            float inv = 1.f/(e0+e1+e2); aw0[0]=e0*inv; aw0[1]=e1*inv; aw0[2]=e2*inv;
        }
        {
            float m = fmaxf(fmaxf(s10,s11),s12);
            float e0 = expf(s10*scl - m*scl), e1 = expf(s11*scl - m*scl), e2 = expf(s12*scl - m*scl);
            float inv = 1.f/(e0+e1+e2); aw1[0]=e0*inv; aw1[1]=e1*inv; aw1[2]=e2*inv;
        }
        {
            float m = fmaxf(fmaxf(s20,s21),s22);
            float e0 = expf(s20*scl - m*scl), e1 = expf(s21*scl - m*scl), e2 = expf(s22*scl - m*scl);
            float inv = 1.f/(e0+e1+e2); aw2[0]=e0*inv; aw2[1]=e1*inv; aw2[2]=e2*inv;
        }
        #pragma unroll
        for (int t = 0; t < 3; ++t) {
            const float a = w0*aw0[t] + w1*aw1[t] + w2*aw2[t];
            AW[(((size_t)b*NH_ + h)*3 + t)*HW_ + hw] = a;
        }
    }
}

// OM[b,c,hw] = sum_t AW[b,h(c),t,hw] * VT[t,b,c,hw]
__global__ __launch_bounds__(256)
void om_combine(const float* __restrict__ VT, const float* __restrict__ AW,
                float* __restrict__ OM) {
    const int gid = blockIdx.x * 256 + threadIdx.x;
    const int hw = gid & (HW_-1);
    const int c  = (gid >> 12) & (C_-1);
    const int b  = gid >> 20;
    const int h  = c >> 5;
    float r = 0.f;
    #pragma unroll
    for (int t = 0; t < 3; ++t)
        r = fmaf(AW[(((size_t)b*NH_ + h)*3 + t)*HW_ + hw],
                 VT[((size_t)(t*B_ + b)*C_ + c)*HW_ + hw], r);
    OM[gid] = r;
}

// ---------------------------------------------------------------------------
extern "C" void kernel_launch(void* const* d_in, const int* in_sizes, int n_in,
                              void* d_out, int out_size, void* d_ws, size_t ws_size,
                              hipStream_t stream) {
    (void)in_sizes; (void)n_in; (void)out_size; (void)ws_size;
    const float* x   = (const float*)d_in[0];
    const float* Wq  = (const float*)d_in[1];
    const float* bq  = (const float*)d_in[2];
    const float* bnq = (const float*)d_in[3];
    const float* Wk  = (const float*)d_in[4];
    const float* bk  = (const float*)d_in[5];
    const float* bnk = (const float*)d_in[6];
    const float* Wv  = (const float*)d_in[7];
    const float* bv  = (const float*)d_in[8];
    const float* bnv = (const float*)d_in[9];
    const float* iw1 = (const float*)d_in[10];
    const float* ib1 = (const float*)d_in[11];
    const float* iw2 = (const float*)d_in[12];
    const float* ib2 = (const float*)d_in[13];
    const float* aiw = (const float*)d_in[14];
    const float* aib = (const float*)d_in[15];
    const float* aow = (const float*)d_in[16];
    const float* aob = (const float*)d_in[17];
    const float* cw  = (const float*)d_in[18];
    const float* cb  = (const float*)d_in[19];
    const float* cbn = (const float*)d_in[20];
    const float* fw2 = (const float*)d_in[21];
    const float* fb2 = (const float*)d_in[22];

    float* ws     = (float*)d_ws;
    float* slot0  = ws + OFF_SLOT0;
    float* slot1  = ws + OFF_SLOT1;
    float* slot2  = ws + OFF_SLOT2;
    float* aw     = ws + OFF_AW;
    float* pooled = ws + OFF_POOL;
    float* hbuf   = ws + OFF_H;
    float* wsm    = ws + OFF_WSM;
    float* out    = (float*)d_out;

    // importance weights
    pool_mean<<<dim3(S_*B_*C_), 256, 0, stream>>>(x, pooled);
    imp1<<<dim3(C_), 256, 0, stream>>>(pooled, iw1, ib1, hbuf);
    imp2<<<dim3(1), 256, 0, stream>>>(hbuf, iw2, ib2, wsm);

    const dim3 g12(HW_/128, C_/128, S_*B_);
    const dim3 g4 (HW_/128, C_/128, B_);

    // Q path: proj (bias+BN+gelu) -> attn-in Q
    gemm_ck<0><<<g12, 256, 0, stream>>>(x, Wq, bq, bnq, nullptr, slot0, 1);
    gemm_ck<1><<<g12, 256, 0, stream>>>(slot0, aiw, aib, nullptr, nullptr, slot1, 0);
    // K path
    gemm_ck<0><<<g12, 256, 0, stream>>>(x, Wk, bk, bnk, nullptr, slot0, 1);
    gemm_ck<1><<<g12, 256, 0, stream>>>(slot0, aiw + C_*C_, aib + C_, nullptr, nullptr, slot2, 0);
    // scores + softmax + importance-fold  (QT=slot1, KT=slot2 -> AW)
    attn_scores<<<dim3(B_*HW_/256), 256, 0, stream>>>(slot1, slot2, wsm, aw);
    // V path
    gemm_ck<0><<<g12, 256, 0, stream>>>(x, Wv, bv, bnv, nullptr, slot0, 1);
    gemm_ck<1><<<g12, 256, 0, stream>>>(slot0, aiw + 2*C_*C_, aib + 2*C_, nullptr, nullptr, slot1, 0);
    // OM[b,c,hw] = sum_t aw * VT   (VT=slot1 -> OM=slot2)
    om_combine<<<dim3(B_*CHW_/256), 256, 0, stream>>>(slot1, aw, slot2);
    // attn out projection (folded over s already): INT = Wout @ OM + bout
    gemm_ck<1><<<g4, 256, 0, stream>>>(slot2, aow, aob, nullptr, nullptr, slot0, 0);
    // 3x3 conv + bias + BN + gelu
    conv3_bn_gelu<<<g4, 256, 0, stream>>>(slot0, cw, cb, cbn, slot1);
    // final 1x1 + bias + residual x[1]
    gemm_ck<2><<<g4, 256, 0, stream>>>(slot1, fw2, fb2, nullptr, x + (size_t)B_*CHW_, out, 0);
}

// Round 5
// 1145.479 us; speedup vs baseline: 1.1159x; 1.1159x over previous
//
#include <hip/hip_runtime.h>
#include <hip/hip_bf16.h>
#include <math.h>

#define S_ 3
#define B_ 4
#define C_ 256
#define H_ 64
#define W_ 64
#define HW_ 4096
#define CHW_ (C_*HW_)
#define NH_ 8
#define HD_ 32
#define EPS_ 1e-5f

static constexpr size_t SLOT      = (size_t)S_ * B_ * CHW_;      // 12,582,912 floats
static constexpr size_t OFF_SLOT0 = 0;
static constexpr size_t OFF_SLOT1 = SLOT;
static constexpr size_t OFF_SLOT2 = 2 * SLOT;
static constexpr size_t OFF_AW    = 3 * SLOT;                    // B*NH*3*HW = 393,216
static constexpr size_t OFF_POOL  = OFF_AW + (size_t)B_*NH_*3*HW_;
static constexpr size_t OFF_H     = OFF_POOL + B_*S_*C_;         // 3072
static constexpr size_t OFF_WSM   = OFF_H + B_*C_;               // 1024

__device__ __forceinline__ float gelu_exact(float x) {
    return 0.5f * x * (1.0f + erff(x * 0.70710678118654752440f));
}

// ---------------------------------------------------------------------------
// pooled[b, s*C + c] = mean over hw of x[s,b,c,:,:]
__global__ __launch_bounds__(256)
void pool_mean(const float* __restrict__ x, float* __restrict__ pooled) {
    const int blk = blockIdx.x;             // (s*B + b)*C + c
    const int c  = blk & (C_-1);
    const int sb = blk >> 8;
    const int s  = sb >> 2, b = sb & 3;
    const float* p = x + (size_t)blk * HW_;
    float sum = 0.f;
    for (int i = threadIdx.x; i < HW_; i += 256) sum += p[i];
    #pragma unroll
    for (int off = 32; off; off >>= 1) sum += __shfl_down(sum, off);
    __shared__ float red[4];
    if ((threadIdx.x & 63) == 0) red[threadIdx.x >> 6] = sum;
    __syncthreads();
    if (threadIdx.x == 0) {
        float t = red[0] + red[1] + red[2] + red[3];
        pooled[b * (S_*C_) + s * C_ + c] = t * (1.0f / HW_);
    }
}

// h[b, o] = gelu(pooled[b,:] . w1[o,:] + b1[o]);   one block per o
__global__ __launch_bounds__(256)
void imp1(const float* __restrict__ pooled, const float* __restrict__ w1,
          const float* __restrict__ b1, float* __restrict__ h) {
    const int o = blockIdx.x;
    const int tid = threadIdx.x;
    float part[4] = {0.f, 0.f, 0.f, 0.f};
    for (int j = tid; j < S_*C_; j += 256) {
        const float wv = w1[o * (S_*C_) + j];
        #pragma unroll
        for (int b = 0; b < 4; ++b) part[b] = fmaf(pooled[b*(S_*C_) + j], wv, part[b]);
    }
    #pragma unroll
    for (int off = 32; off; off >>= 1)
        #pragma unroll
        for (int b = 0; b < 4; ++b) part[b] += __shfl_down(part[b], off);
    __shared__ float red[4][4];
    if ((tid & 63) == 0) {
        #pragma unroll
        for (int b = 0; b < 4; ++b) red[tid >> 6][b] = part[b];
    }
    __syncthreads();
    if (tid < 4) {
        float t = red[0][tid] + red[1][tid] + red[2][tid] + red[3][tid];
        h[tid * C_ + o] = gelu_exact(t + b1[o]);
    }
}

// w[b, s] = softmax_s(h[b,:] . w2[s,:] + b2[s])
__global__ __launch_bounds__(256)
void imp2(const float* __restrict__ h, const float* __restrict__ w2,
          const float* __restrict__ b2, float* __restrict__ wout) {
    __shared__ float hl[B_*C_];
    __shared__ float lg[4][3];
    const int tid = threadIdx.x;
    for (int i = tid; i < B_*C_; i += 256) hl[i] = h[i];
    __syncthreads();
    if (tid < 12) {
        const int b = tid / 3, s = tid % 3;
        float a = b2[s];
        for (int o = 0; o < C_; ++o) a = fmaf(hl[b*C_ + o], w2[s*C_ + o], a);
        lg[b][s] = a;
    }
    __syncthreads();
    if (tid < 4) {
        const float m = fmaxf(fmaxf(lg[tid][0], lg[tid][1]), lg[tid][2]);
        const float e0 = expf(lg[tid][0]-m), e1 = expf(lg[tid][1]-m), e2 = expf(lg[tid][2]-m);
        const float inv = 1.0f / (e0 + e1 + e2);
        wout[tid*3+0] = e0*inv; wout[tid*3+1] = e1*inv; wout[tid*3+2] = e2*inv;
    }
}

// ---------------------------------------------------------------------------
// Channel GEMM: Out[z][o][n] = sum_c W[o,c] * In[z][c][n]  (+ epilogue)
// MODE 0: +bias, BN, exact gelu (params indexed widx = perS ? z>>2 : 0)
// MODE 1: +bias
// MODE 2: +bias +resid[z]
// N-microtile split into two float4 groups (tx*4 and 64+tx*4): 16 lanes read
// 256 B contiguous per instr -> 2 lanes/bank -> conflict-free.
template<int MODE>
__global__ __launch_bounds__(256)
void gemm_ck(const float* __restrict__ In, const float* __restrict__ Wb,
             const float* __restrict__ bias, const float* __restrict__ bnp,
             const float* __restrict__ resid, float* __restrict__ Out,
             int perS) {
    __shared__ float Wt[16][132];
    __shared__ float It[16][132];

    const int z = blockIdx.z;
    const int widx = perS ? (z >> 2) : 0;
    const float* Wm = Wb + (size_t)widx * (C_*C_);
    const float* bp = bias + (size_t)widx * C_;
    const float* in = In + (size_t)z * CHW_;
    float* out = Out + (size_t)z * CHW_;

    const int tid = threadIdx.x;
    const int tx = tid & 15;       // n group
    const int ty = tid >> 4;       // m group
    const int nBase = blockIdx.x * 128;
    const int mBase = blockIdx.y * 128;

    float acc[8][8];
    #pragma unroll
    for (int i = 0; i < 8; ++i)
        #pragma unroll
        for (int j = 0; j < 8; ++j) acc[i][j] = 0.f;

    for (int k0 = 0; k0 < C_; k0 += 16) {
        #pragma unroll
        for (int it = 0; it < 2; ++it) {              // W tile: 128 x 16, transposed
            const int idx = tid + it*256;
            const int m  = idx >> 2;
            const int c4 = (idx & 3) << 2;
            const float4 v = *(const float4*)&Wm[(size_t)(mBase+m)*C_ + k0 + c4];
            Wt[c4+0][m] = v.x; Wt[c4+1][m] = v.y; Wt[c4+2][m] = v.z; Wt[c4+3][m] = v.w;
        }
        #pragma unroll
        for (int it = 0; it < 2; ++it) {              // In tile: 16 x 128
            const int idx = tid + it*256;
            const int r  = idx >> 5;
            const int c4 = (idx & 31) << 2;
            *(float4*)&It[r][c4] = *(const float4*)&in[(size_t)(k0+r)*HW_ + nBase + c4];
        }
        __syncthreads();
        #pragma unroll
        for (int k = 0; k < 16; ++k) {
            float a[8], b[8];
            *(float4*)&a[0] = *(const float4*)&Wt[k][ty*8];
            *(float4*)&a[4] = *(const float4*)&Wt[k][ty*8+4];
            *(float4*)&b[0] = *(const float4*)&It[k][tx*4];
            *(float4*)&b[4] = *(const float4*)&It[k][64 + tx*4];
            #pragma unroll
            for (int i = 0; i < 8; ++i)
                #pragma unroll
                for (int j = 0; j < 8; ++j)
                    acc[i][j] = fmaf(a[i], b[j], acc[i][j]);
        }
        __syncthreads();
    }

    #pragma unroll
    for (int i = 0; i < 8; ++i) {
        const int o = mBase + ty*8 + i;
        const float bi = bp[o];
        float mulc = 1.f, addc = bi;
        if constexpr (MODE == 0) {
            const float g  = bnp[(size_t)widx*4*C_ + o];
            const float be = bnp[(size_t)widx*4*C_ + C_   + o];
            const float mu = bnp[(size_t)widx*4*C_ + 2*C_ + o];
            const float va = bnp[(size_t)widx*4*C_ + 3*C_ + o];
            mulc = g * rsqrtf(va + EPS_);
            addc = (bi - mu) * mulc + be;
        }
        const size_t row = (size_t)o * HW_ + nBase + tx*4;
        float y[8];
        #pragma unroll
        for (int j = 0; j < 8; ++j) {
            float v = fmaf(acc[i][j], mulc, addc);
            if constexpr (MODE == 0) v = gelu_exact(v);
            y[j] = v;
        }
        if constexpr (MODE == 2) {
            const float4 q0 = *(const float4*)&resid[(size_t)z*CHW_ + row];
            const float4 q1 = *(const float4*)&resid[(size_t)z*CHW_ + row + 64];
            y[0]+=q0.x; y[1]+=q0.y; y[2]+=q0.z; y[3]+=q0.w;
            y[4]+=q1.x; y[5]+=q1.y; y[6]+=q1.z; y[7]+=q1.w;
        }
        *(float4*)&out[row]      = make_float4(y[0],y[1],y[2],y[3]);
        *(float4*)&out[row + 64] = make_float4(y[4],y[5],y[6],y[7]);
    }
}

// ---------------------------------------------------------------------------
// 3x3 SAME conv as flat-K implicit GEMM (K = C*9 = 2304, k = c*9 + tap).
// Wc[o][c][ky][kx] is contiguous in flat k -> coalesced float4 weight loads.
// Tile M=128 x N=64 (N-tile = exactly one image row -> whole-row y masking),
// BK=32, grid (64,2,B) = 512 blocks -> 2 blocks/CU, 8 waves/CU.
__global__ __launch_bounds__(256)
void conv3_bn_gelu(const float* __restrict__ In, const float* __restrict__ Wc,
                   const float* __restrict__ bias, const float* __restrict__ bnp,
                   float* __restrict__ Out) {
    __shared__ float Wt[32][132];   // [k][m], m=128 (+4 pad)
    __shared__ float It[32][68];    // [k][n], n=64  (+4 pad)

    const int b = blockIdx.z;
    const float* in = In + (size_t)b * CHW_;
    float* out = Out + (size_t)b * CHW_;

    const int tid = threadIdx.x;
    const int tx = tid & 15;       // n group: 4 cols each
    const int ty = tid >> 4;       // m group: 8 rows each
    const int nBase = blockIdx.x * 64;    // 64 n-tiles (one image row each)
    const int mBase = blockIdx.y * 128;   // 2 m-tiles
    const int yrow  = blockIdx.x;         // image row of this n-tile

    float acc[8][4];
    #pragma unroll
    for (int i = 0; i < 8; ++i)
        #pragma unroll
        for (int j = 0; j < 4; ++j) acc[i][j] = 0.f;

    for (int k0 = 0; k0 < 9*C_; k0 += 32) {
        // ---- stage W: 128 rows x 32 k, coalesced float4, store transposed
        #pragma unroll
        for (int it = 0; it < 4; ++it) {
            const int fidx = tid + it*256;          // 1024 float4s
            const int o  = fidx >> 3;
            const int kc = (fidx & 7) << 2;
            const float4 v = *(const float4*)&Wc[(size_t)(mBase+o)*(9*C_) + k0 + kc];
            Wt[kc+0][o]=v.x; Wt[kc+1][o]=v.y; Wt[kc+2][o]=v.z; Wt[kc+3][o]=v.w;
        }
        // ---- stage input: 32 k-rows x 64 cols, shifted + masked
        #pragma unroll
        for (int it = 0; it < 8; ++it) {
            const int idx = tid + it*256;           // 2048 elems
            const int r = idx >> 6;
            const int n = idx & 63;
            const int k = k0 + r;
            const int c   = k / 9;
            const int tap = k - c*9;
            const int t3  = tap / 3;
            const int dy = t3 - 1;
            const int dx = tap - t3*3 - 1;
            const int sy = yrow + dy;
            const int sx = n + dx;
            float v = 0.f;
            if ((unsigned)sy < (unsigned)H_ && (unsigned)sx < (unsigned)W_)
                v = in[(size_t)c*HW_ + sy*W_ + sx];
            It[r][n] = v;
        }
        __syncthreads();
        #pragma unroll
        for (int k = 0; k < 32; ++k) {
            float a[8], bb[4];
            *(float4*)&a[0]  = *(const float4*)&Wt[k][ty*8];
            *(float4*)&a[4]  = *(const float4*)&Wt[k][ty*8+4];
            *(float4*)&bb[0] = *(const float4*)&It[k][tx*4];
            #pragma unroll
            for (int i = 0; i < 8; ++i)
                #pragma unroll
                for (int j = 0; j < 4; ++j)
                    acc[i][j] = fmaf(a[i], bb[j], acc[i][j]);
        }
        __syncthreads();
    }

    #pragma unroll
    for (int i = 0; i < 8; ++i) {
        const int o = mBase + ty*8 + i;
        const float g  = bnp[o];
        const float be = bnp[C_   + o];
        const float mu = bnp[2*C_ + o];
        const float va = bnp[3*C_ + o];
        const float mulc = g * rsqrtf(va + EPS_);
        const float addc = (bias[o] - mu) * mulc + be;
        const size_t row = (size_t)o * HW_ + nBase + tx*4;
        float y[4];
        #pragma unroll
        for (int j = 0; j < 4; ++j) y[j] = gelu_exact(fmaf(acc[i][j], mulc, addc));
        *(float4*)&out[row] = make_float4(y[0],y[1],y[2],y[3]);
    }
}

// ---------------------------------------------------------------------------
// Per-token-head: scores = qt.kt^T/sqrt(HD); softmax over t;
// aw[b,h,t,hw] = sum_s w[b,s]*attn[s,t]
__global__ __launch_bounds__(256)
void attn_scores(const float* __restrict__ QT, const float* __restrict__ KT,
                 const float* __restrict__ wsm, float* __restrict__ AW) {
    const int gid = blockIdx.x * 256 + threadIdx.x;
    const int b  = gid >> 12;
    const int hw = gid & (HW_-1);
    const float w0 = wsm[b*3+0], w1 = wsm[b*3+1], w2 = wsm[b*3+2];
    const size_t sStride = (size_t)B_ * CHW_;
    for (int h = 0; h < NH_; ++h) {
        const size_t base = ((size_t)b*C_ + h*HD_)*HW_ + hw;
        float s00=0,s01=0,s02=0,s10=0,s11=0,s12=0,s20=0,s21=0,s22=0;
        #pragma unroll 8
        for (int d = 0; d < HD_; ++d) {
            const size_t off = base + (size_t)d*HW_;
            const float q0 = QT[off], q1 = QT[off+sStride], q2 = QT[off+2*sStride];
            const float k0 = KT[off], k1 = KT[off+sStride], k2 = KT[off+2*sStride];
            s00 = fmaf(q0,k0,s00); s01 = fmaf(q0,k1,s01); s02 = fmaf(q0,k2,s02);
            s10 = fmaf(q1,k0,s10); s11 = fmaf(q1,k1,s11); s12 = fmaf(q1,k2,s12);
            s20 = fmaf(q2,k0,s20); s21 = fmaf(q2,k1,s21); s22 = fmaf(q2,k2,s22);
        }
        const float scl = 0.17677669529663687f;   // 1/sqrt(32)
        float aw0[3], aw1[3], aw2[3];
        {
            float m = fmaxf(fmaxf(s00,s01),s02);
            float e0 = expf(s00*scl - m*scl), e1 = expf(s01*scl - m*scl), e2 = expf(s02*scl - m*scl);
            float inv = 1.f/(e0+e1+e2); aw0[0]=e0*inv; aw0[1]=e1*inv; aw0[2]=e2*inv;
        }
        {
            float m = fmaxf(fmaxf(s10,s11),s12);
            float e0 = expf(s10*scl - m*scl), e1 = expf(s11*scl - m*scl), e2 = expf(s12*scl - m*scl);
            float inv = 1.f/(e0+e1+e2); aw1[0]=e0*inv; aw1[1]=e1*inv; aw1[2]=e2*inv;
        }
        {
            float m = fmaxf(fmaxf(s20,s21),s22);
            float e0 = expf(s20*scl - m*scl), e1 = expf(s21*scl - m*scl), e2 = expf(s22*scl - m*scl);
            float inv = 1.f/(e0+e1+e2); aw2[0]=e0*inv; aw2[1]=e1*inv; aw2[2]=e2*inv;
        }
        #pragma unroll
        for (int t = 0; t < 3; ++t) {
            const float a = w0*aw0[t] + w1*aw1[t] + w2*aw2[t];
            AW[(((size_t)b*NH_ + h)*3 + t)*HW_ + hw] = a;
        }
    }
}

// OM[b,c,hw] = sum_t AW[b,h(c),t,hw] * VT[t,b,c,hw]
__global__ __launch_bounds__(256)
void om_combine(const float* __restrict__ VT, const float* __restrict__ AW,
                float* __restrict__ OM) {
    const int gid = blockIdx.x * 256 + threadIdx.x;
    const int hw = gid & (HW_-1);
    const int c  = (gid >> 12) & (C_-1);
    const int b  = gid >> 20;
    const int h  = c >> 5;
    float r = 0.f;
    #pragma unroll
    for (int t = 0; t < 3; ++t)
        r = fmaf(AW[(((size_t)b*NH_ + h)*3 + t)*HW_ + hw],
                 VT[((size_t)(t*B_ + b)*C_ + c)*HW_ + hw], r);
    OM[gid] = r;
}

// ---------------------------------------------------------------------------
extern "C" void kernel_launch(void* const* d_in, const int* in_sizes, int n_in,
                              void* d_out, int out_size, void* d_ws, size_t ws_size,
                              hipStream_t stream) {
    (void)in_sizes; (void)n_in; (void)out_size; (void)ws_size;
    const float* x   = (const float*)d_in[0];
    const float* Wq  = (const float*)d_in[1];
    const float* bq  = (const float*)d_in[2];
    const float* bnq = (const float*)d_in[3];
    const float* Wk  = (const float*)d_in[4];
    const float* bk  = (const float*)d_in[5];
    const float* bnk = (const float*)d_in[6];
    const float* Wv  = (const float*)d_in[7];
    const float* bv  = (const float*)d_in[8];
    const float* bnv = (const float*)d_in[9];
    const float* iw1 = (const float*)d_in[10];
    const float* ib1 = (const float*)d_in[11];
    const float* iw2 = (const float*)d_in[12];
    const float* ib2 = (const float*)d_in[13];
    const float* aiw = (const float*)d_in[14];
    const float* aib = (const float*)d_in[15];
    const float* aow = (const float*)d_in[16];
    const float* aob = (const float*)d_in[17];
    const float* cw  = (const float*)d_in[18];
    const float* cb  = (const float*)d_in[19];
    const float* cbn = (const float*)d_in[20];
    const float* fw2 = (const float*)d_in[21];
    const float* fb2 = (const float*)d_in[22];

    float* ws     = (float*)d_ws;
    float* slot0  = ws + OFF_SLOT0;
    float* slot1  = ws + OFF_SLOT1;
    float* slot2  = ws + OFF_SLOT2;
    float* aw     = ws + OFF_AW;
    float* pooled = ws + OFF_POOL;
    float* hbuf   = ws + OFF_H;
    float* wsm    = ws + OFF_WSM;
    float* out    = (float*)d_out;

    // importance weights
    pool_mean<<<dim3(S_*B_*C_), 256, 0, stream>>>(x, pooled);
    imp1<<<dim3(C_), 256, 0, stream>>>(pooled, iw1, ib1, hbuf);
    imp2<<<dim3(1), 256, 0, stream>>>(hbuf, iw2, ib2, wsm);

    const dim3 g12(HW_/128, C_/128, S_*B_);
    const dim3 g4 (HW_/128, C_/128, B_);
    const dim3 gc (H_, C_/128, B_);

    // Q path: proj (bias+BN+gelu) -> attn-in Q
    gemm_ck<0><<<g12, 256, 0, stream>>>(x, Wq, bq, bnq, nullptr, slot0, 1);
    gemm_ck<1><<<g12, 256, 0, stream>>>(slot0, aiw, aib, nullptr, nullptr, slot1, 0);
    // K path
    gemm_ck<0><<<g12, 256, 0, stream>>>(x, Wk, bk, bnk, nullptr, slot0, 1);
    gemm_ck<1><<<g12, 256, 0, stream>>>(slot0, aiw + C_*C_, aib + C_, nullptr, nullptr, slot2, 0);
    // scores + softmax + importance-fold  (QT=slot1, KT=slot2 -> AW)
    attn_scores<<<dim3(B_*HW_/256), 256, 0, stream>>>(slot1, slot2, wsm, aw);
    // V path
    gemm_ck<0><<<g12, 256, 0, stream>>>(x, Wv, bv, bnv, nullptr, slot0, 1);
    gemm_ck<1><<<g12, 256, 0, stream>>>(slot0, aiw + 2*C_*C_, aib + 2*C_, nullptr, nullptr, slot1, 0);
    // OM[b,c,hw] = sum_t aw * VT   (VT=slot1 -> OM=slot2)
    om_combine<<<dim3(B_*CHW_/256), 256, 0, stream>>>(slot1, aw, slot2);
    // attn out projection (folded over s already): INT = Wout @ OM + bout
    gemm_ck<1><<<g4, 256, 0, stream>>>(slot2, aow, aob, nullptr, nullptr, slot0, 0);
    // 3x3 conv + bias + BN + gelu (flat-K implicit GEMM)
    conv3_bn_gelu<<<gc, 256, 0, stream>>>(slot0, cw, cb, cbn, slot1);
    // final 1x1 + bias + residual x[1]
    gemm_ck<2><<<g4, 256, 0, stream>>>(slot1, fw2, fb2, nullptr, x + (size_t)B_*CHW_, out, 0);
}

// Round 6
// 452.226 us; speedup vs baseline: 2.8265x; 2.5330x over previous
//
#include <hip/hip_runtime.h>
#include <hip/hip_bf16.h>
#include <math.h>

#define S_ 3
#define B_ 4
#define C_ 256
#define H_ 64
#define W_ 64
#define HW_ 4096
#define CHW_ (C_*HW_)
#define NH_ 8
#define HD_ 32
#define EPS_ 1e-5f

typedef float  f32x4 __attribute__((ext_vector_type(4)));
typedef short  s16x8 __attribute__((ext_vector_type(8)));
typedef unsigned short u16x4 __attribute__((ext_vector_type(4)));
typedef unsigned int   u32x2 __attribute__((ext_vector_type(2)));
typedef int    s32x4 __attribute__((ext_vector_type(4)));

// ---- workspace layout (bytes) -------------------------------------------
static constexpr size_t HALFB  = (size_t)S_*B_*CHW_*2;   // bf16 S*B*C*HW = 25,165,824 B
static constexpr size_t QB     = (size_t)B_*CHW_*2;      // bf16 B*C*HW   =  8,388,608 B
static constexpr size_t O_XB   = 0;
static constexpr size_t O_S0B  = HALFB;
static constexpr size_t O_BUFA = 2*HALFB;
static constexpr size_t O_BUFB = 3*HALFB;
static constexpr size_t O_OMB  = 4*HALFB;
static constexpr size_t O_INTB = 4*HALFB + QB;
static constexpr size_t O_CVB  = 4*HALFB + 2*QB;
static constexpr size_t O_AW   = 4*HALFB + 3*QB;                   // float B*NH*3*HW
static constexpr size_t O_WB   = O_AW + (size_t)B_*NH_*3*HW_*4;    // bf16 packed weights
static constexpr size_t WB_ELEMS = 1507328;
static constexpr size_t O_POOL = O_WB + WB_ELEMS*2;
static constexpr size_t O_H    = O_POOL + (size_t)B_*S_*C_*4;
static constexpr size_t O_WSM  = O_H + (size_t)B_*C_*4;
// packed bf16 weight element offsets
static constexpr size_t WO_WQ  = 0;
static constexpr size_t WO_WK  = 196608;
static constexpr size_t WO_WV  = 393216;
static constexpr size_t WO_AIW = 589824;
static constexpr size_t WO_AOW = 786432;
static constexpr size_t WO_CW  = 851968;
static constexpr size_t WO_FW2 = 1441792;

__device__ __forceinline__ float gelu_exact(float x) {
    return 0.5f * x * (1.0f + erff(x * 0.70710678118654752440f));
}
__device__ __forceinline__ unsigned short f2bf(float f) {
    union { float f; unsigned u; } x; x.f = f;
    unsigned r = x.u + 0x7FFFu + ((x.u >> 16) & 1u);
    return (unsigned short)(r >> 16);
}
__device__ __forceinline__ float bf2f(unsigned short h) {
    union { unsigned u; float f; } x; x.u = ((unsigned)h) << 16;
    return x.f;
}

// ---------------------------------------------------------------------------
// cast all weight matrices fp32 -> bf16 into packed region
__global__ __launch_bounds__(256)
void cast_w(const float* __restrict__ w0, const float* __restrict__ w1,
            const float* __restrict__ w2, const float* __restrict__ w3,
            const float* __restrict__ w4, const float* __restrict__ w5,
            const float* __restrict__ w6, unsigned short* __restrict__ dst) {
    int blk = blockIdx.x;
    const float* src; size_t base;
    if      (blk < 48)  { src = w0; base = WO_WQ;  }
    else if (blk < 96)  { src = w1; base = WO_WK;  blk -= 48; }
    else if (blk < 144) { src = w2; base = WO_WV;  blk -= 96; }
    else if (blk < 192) { src = w3; base = WO_AIW; blk -= 144; }
    else if (blk < 208) { src = w4; base = WO_AOW; blk -= 192; }
    else if (blk < 352) { src = w5; base = WO_CW;  blk -= 208; }
    else                { src = w6; base = WO_FW2; blk -= 352; }
    size_t off = (size_t)blk*4096 + threadIdx.x*4;
    #pragma unroll
    for (int it = 0; it < 4; ++it, off += 1024) {
        float4 v = *(const float4*)&src[off];
        u16x4 h; h[0] = f2bf(v.x); h[1] = f2bf(v.y); h[2] = f2bf(v.z); h[3] = f2bf(v.w);
        *(u16x4*)&dst[base + off] = h;
    }
}

// ---------------------------------------------------------------------------
// fused: cast x -> bf16 AND pooled[b, s*C+c] = mean_hw x[s,b,c,:,:]
__global__ __launch_bounds__(256)
void cast_pool(const float* __restrict__ x, unsigned short* __restrict__ xb,
               float* __restrict__ pooled) {
    const int blk = blockIdx.x;             // (s*B + b)*C + c
    const int c  = blk & (C_-1);
    const int sb = blk >> 8;
    const int s  = sb >> 2, b = sb & 3;
    const float* p = x + (size_t)blk * HW_;
    unsigned short* q = xb + (size_t)blk * HW_;
    float sum = 0.f;
    int i = threadIdx.x * 4;
    #pragma unroll
    for (int it = 0; it < 4; ++it, i += 1024) {
        float4 v = *(const float4*)&p[i];
        sum += v.x + v.y + v.z + v.w;
        u16x4 h; h[0] = f2bf(v.x); h[1] = f2bf(v.y); h[2] = f2bf(v.z); h[3] = f2bf(v.w);
        *(u16x4*)&q[i] = h;
    }
    #pragma unroll
    for (int off = 32; off; off >>= 1) sum += __shfl_down(sum, off);
    __shared__ float red[4];
    if ((threadIdx.x & 63) == 0) red[threadIdx.x >> 6] = sum;
    __syncthreads();
    if (threadIdx.x == 0) {
        float t = red[0] + red[1] + red[2] + red[3];
        pooled[b * (S_*C_) + s * C_ + c] = t * (1.0f / HW_);
    }
}

// h[b, o] = gelu(pooled[b,:] . w1[o,:] + b1[o]);   one block per o
__global__ __launch_bounds__(256)
void imp1(const float* __restrict__ pooled, const float* __restrict__ w1,
          const float* __restrict__ b1, float* __restrict__ h) {
    const int o = blockIdx.x;
    const int tid = threadIdx.x;
    float part[4] = {0.f, 0.f, 0.f, 0.f};
    for (int j = tid; j < S_*C_; j += 256) {
        const float wv = w1[o * (S_*C_) + j];
        #pragma unroll
        for (int b = 0; b < 4; ++b) part[b] = fmaf(pooled[b*(S_*C_) + j], wv, part[b]);
    }
    #pragma unroll
    for (int off = 32; off; off >>= 1)
        #pragma unroll
        for (int b = 0; b < 4; ++b) part[b] += __shfl_down(part[b], off);
    __shared__ float red[4][4];
    if ((tid & 63) == 0) {
        #pragma unroll
        for (int b = 0; b < 4; ++b) red[tid >> 6][b] = part[b];
    }
    __syncthreads();
    if (tid < 4) {
        float t = red[0][tid] + red[1][tid] + red[2][tid] + red[3][tid];
        h[tid * C_ + o] = gelu_exact(t + b1[o]);
    }
}

// w[b, s] = softmax_s(h[b,:] . w2[s,:] + b2[s])
__global__ __launch_bounds__(256)
void imp2(const float* __restrict__ h, const float* __restrict__ w2,
          const float* __restrict__ b2, float* __restrict__ wout) {
    __shared__ float hl[B_*C_];
    __shared__ float lg[4][3];
    const int tid = threadIdx.x;
    for (int i = tid; i < B_*C_; i += 256) hl[i] = h[i];
    __syncthreads();
    if (tid < 12) {
        const int b = tid / 3, s = tid % 3;
        float a = b2[s];
        for (int o = 0; o < C_; ++o) a = fmaf(hl[b*C_ + o], w2[s*C_ + o], a);
        lg[b][s] = a;
    }
    __syncthreads();
    if (tid < 4) {
        const float m = fmaxf(fmaxf(lg[tid][0], lg[tid][1]), lg[tid][2]);
        const float e0 = expf(lg[tid][0]-m), e1 = expf(lg[tid][1]-m), e2 = expf(lg[tid][2]-m);
        const float inv = 1.0f / (e0 + e1 + e2);
        wout[tid*3+0] = e0*inv; wout[tid*3+1] = e1*inv; wout[tid*3+2] = e2*inv;
    }
}

// ---------------------------------------------------------------------------
// bf16 MFMA channel GEMM: Out[z][o][n] = sum_c W[o,c]*In[z][c][n] (+epilogue)
// Tile 128x128, BK=32, 4 waves (2x2), frag-packed LDS (contiguous b128 reads).
// MODE 0: bias+BN+gelu -> bf16 out;  MODE 1: bias -> bf16 out;
// MODE 2: bias + resid -> fp32 out.
template<int MODE>
__global__ __launch_bounds__(256)
void mgemm(const unsigned short* __restrict__ In, const unsigned short* __restrict__ Wb,
           const float* __restrict__ bias, const float* __restrict__ bnp,
           const float* __restrict__ resid, void* __restrict__ Out, int perS) {
    __shared__ __align__(16) unsigned short Ash[4096];   // 128m x 32k frag-packed
    __shared__ __align__(16) unsigned short Bsh[4096];   // 32k x 128n frag-packed
    __shared__ float2 ep[128];

    const int z    = blockIdx.z;
    const int widx = perS ? (z >> 2) : 0;
    const unsigned short* Wm = Wb + (size_t)widx * (C_*C_);
    const unsigned short* in = In + (size_t)z * CHW_;
    const int tid  = threadIdx.x;
    const int lane = tid & 63;
    const int wid  = tid >> 6;
    const int nBase = blockIdx.x * 128;
    const int mBase = blockIdx.y * 128;
    const int wm = (wid >> 1) * 64;   // wave row offset in tile
    const int wn = (wid & 1) * 64;    // wave col offset in tile

    if (tid < 128) {
        const int o = mBase + tid;
        float mulc = 1.f, addc = bias[widx*C_ + o];
        if constexpr (MODE == 0) {
            const float g  = bnp[(size_t)widx*4*C_ + o];
            const float be = bnp[(size_t)widx*4*C_ + C_   + o];
            const float mu = bnp[(size_t)widx*4*C_ + 2*C_ + o];
            const float va = bnp[(size_t)widx*4*C_ + 3*C_ + o];
            mulc = g * rsqrtf(va + EPS_);
            addc = (addc - mu) * mulc + be;
        }
        ep[tid] = make_float2(mulc, addc);
    }

    const f32x4 zero = {0.f, 0.f, 0.f, 0.f};
    f32x4 acc[4][4];
    #pragma unroll
    for (int i = 0; i < 4; ++i)
        #pragma unroll
        for (int j = 0; j < 4; ++j) acc[i][j] = zero;

    for (int k0 = 0; k0 < C_; k0 += 32) {
        __syncthreads();
        // ---- stage A (bf16 weights): unit = (m, k-quad q)
        #pragma unroll
        for (int it = 0; it < 4; ++it) {
            const int idx = tid + it*256;
            const int m = idx >> 3, q = idx & 7;
            u16x4 v = *(const u16x4*)&Wm[(size_t)(mBase + m)*C_ + k0 + 4*q];
            u32x2 w; w[0] = (unsigned)v[0] | ((unsigned)v[1] << 16);
                     w[1] = (unsigned)v[2] | ((unsigned)v[3] << 16);
            *(u32x2*)((char*)Ash + ((m>>4)*1024 + ((m&15) + 16*(q>>1))*16 + (q&1)*8)) = w;
        }
        // ---- stage B (bf16 activations): unit = (n, k-quad kq), k-strided loads
        #pragma unroll
        for (int it = 0; it < 4; ++it) {
            const int idx = tid + it*256;
            const int n = idx & 127, kq = idx >> 7;
            const size_t gb = (size_t)(k0 + 4*kq)*HW_ + nBase + n;
            unsigned short e0 = in[gb], e1 = in[gb + HW_], e2 = in[gb + 2*HW_], e3 = in[gb + 3*HW_];
            u32x2 w; w[0] = (unsigned)e0 | ((unsigned)e1 << 16);
                     w[1] = (unsigned)e2 | ((unsigned)e3 << 16);
            *(u32x2*)((char*)Bsh + ((n>>4)*1024 + ((n&15) + 16*(kq>>1))*16 + (kq&1)*8)) = w;
        }
        __syncthreads();
        // ---- compute: 16 MFMA per wave
        s16x8 af[4], bfv[4];
        #pragma unroll
        for (int mi = 0; mi < 4; ++mi)
            af[mi] = *(const s16x8*)((const char*)Ash + (((wm>>4) + mi)*1024 + lane*16));
        #pragma unroll
        for (int ni = 0; ni < 4; ++ni)
            bfv[ni] = *(const s16x8*)((const char*)Bsh + (((wn>>4) + ni)*1024 + lane*16));
        #pragma unroll
        for (int mi = 0; mi < 4; ++mi)
            #pragma unroll
            for (int ni = 0; ni < 4; ++ni)
                acc[mi][ni] = __builtin_amdgcn_mfma_f32_16x16x32_bf16(af[mi], bfv[ni], acc[mi][ni], 0, 0, 0);
    }

    // ---- epilogue: D row = 4*(lane>>4)+j, col = lane&15 (verified layout)
    const int cb = wn + (lane & 15);
    const int r0 = (lane >> 4) * 4;
    if constexpr (MODE == 2) {
        float* out = (float*)Out + (size_t)z * CHW_;
        const float* rs = resid + (size_t)z * CHW_;
        #pragma unroll
        for (int mi = 0; mi < 4; ++mi)
            #pragma unroll
            for (int j = 0; j < 4; ++j) {
                const int ro = wm + mi*16 + r0 + j;
                const float2 ma = ep[ro];
                const size_t row = (size_t)(mBase + ro)*HW_ + nBase;
                #pragma unroll
                for (int ni = 0; ni < 4; ++ni) {
                    const int n = cb + ni*16;
                    out[row + n] = fmaf(acc[mi][ni][j], ma.x, ma.y) + rs[row + n];
                }
            }
    } else {
        unsigned short* out = (unsigned short*)Out + (size_t)z * CHW_;
        #pragma unroll
        for (int mi = 0; mi < 4; ++mi)
            #pragma unroll
            for (int j = 0; j < 4; ++j) {
                const int ro = wm + mi*16 + r0 + j;
                const float2 ma = ep[ro];
                const size_t row = (size_t)(mBase + ro)*HW_ + nBase;
                #pragma unroll
                for (int ni = 0; ni < 4; ++ni) {
                    const int n = cb + ni*16;
                    float v = fmaf(acc[mi][ni][j], ma.x, ma.y);
                    if constexpr (MODE == 0) v = gelu_exact(v);
                    out[row + n] = f2bf(v);
                }
            }
    }
}

// ---------------------------------------------------------------------------
// 3x3 SAME conv as bf16 MFMA implicit GEMM, flat K = C*9 = 2304.
// Tile 128(o) x 64(n = one image row), BK=32, 4 waves (2m x 2n).
// Per-k (offset,mask) table precomputed in LDS. + bias + BN + gelu -> bf16.
__global__ __launch_bounds__(256)
void conv_mfma(const unsigned short* __restrict__ In, const unsigned short* __restrict__ Wc,
               const float* __restrict__ bias, const float* __restrict__ bnp,
               unsigned short* __restrict__ Out) {
    __shared__ __align__(16) int T[9*C_];                 // per-k: dy,dx,offset packed
    __shared__ __align__(16) unsigned short Ash[4096];    // 128m x 32k frag-packed
    __shared__ __align__(16) unsigned short Bsh[2048];    // 32k x 64n frag-packed
    __shared__ float2 ep[128];

    const int b = blockIdx.z;
    const unsigned short* in = In + (size_t)b * CHW_;
    const int tid  = threadIdx.x;
    const int lane = tid & 63;
    const int wid  = tid >> 6;
    const int yrow  = blockIdx.x;          // image row (n-tile)
    const int mBase = blockIdx.y * 128;
    const int wm = (wid >> 1) * 64;
    const int wn = (wid & 1) * 32;

    for (int kk = tid; kk < 9*C_; kk += 256) {
        const int c   = kk / 9;
        const int tap = kk - 9*c;
        const int t3  = tap / 3;
        const int dx  = tap - t3*3 - 1;
        const int off = c*HW_ + (t3 - 1)*W_ + dx;
        T[kk] = (t3 << 22) | ((dx + 1) << 20) | (off + 65);
    }
    if (tid < 128) {
        const int o = mBase + tid;
        const float g  = bnp[o];
        const float be = bnp[C_   + o];
        const float mu = bnp[2*C_ + o];
        const float va = bnp[3*C_ + o];
        const float mulc = g * rsqrtf(va + EPS_);
        ep[tid] = make_float2(mulc, (bias[o] - mu) * mulc + be);
    }

    const f32x4 zero = {0.f, 0.f, 0.f, 0.f};
    f32x4 acc[4][2];
    #pragma unroll
    for (int i = 0; i < 4; ++i) { acc[i][0] = zero; acc[i][1] = zero; }

    const int base2 = yrow*W_;   // + n added per element

    for (int k0 = 0; k0 < 9*C_; k0 += 32) {
        __syncthreads();
        // ---- stage A (bf16 conv weights, flat-k contiguous)
        #pragma unroll
        for (int it = 0; it < 4; ++it) {
            const int idx = tid + it*256;
            const int m = idx >> 3, q = idx & 7;
            u16x4 v = *(const u16x4*)&Wc[(size_t)(mBase + m)*(9*C_) + k0 + 4*q];
            u32x2 w; w[0] = (unsigned)v[0] | ((unsigned)v[1] << 16);
                     w[1] = (unsigned)v[2] | ((unsigned)v[3] << 16);
            *(u32x2*)((char*)Ash + ((m>>4)*1024 + ((m&15) + 16*(q>>1))*16 + (q&1)*8)) = w;
        }
        // ---- stage B: shifted/masked bf16 input via table
        #pragma unroll
        for (int it = 0; it < 2; ++it) {
            const int idx = tid + it*256;
            const int n = idx & 63, kq = idx >> 6;
            s32x4 tv = *(const s32x4*)&T[k0 + 4*kq];
            unsigned short e[4];
            #pragma unroll
            for (int j = 0; j < 4; ++j) {
                const int v  = tv[j];
                const int sy = yrow + ((v >> 22) & 3) - 1;
                const int sx = n    + ((v >> 20) & 3) - 1;
                const int off = (v & 0xFFFFF) - 65;
                e[j] = ((unsigned)sy < (unsigned)H_ && (unsigned)sx < (unsigned)W_)
                       ? in[off + base2 + n] : (unsigned short)0;
            }
            u32x2 w; w[0] = (unsigned)e[0] | ((unsigned)e[1] << 16);
                     w[1] = (unsigned)e[2] | ((unsigned)e[3] << 16);
            *(u32x2*)((char*)Bsh + ((n>>4)*1024 + ((n&15) + 16*(kq>>1))*16 + (kq&1)*8)) = w;
        }
        __syncthreads();
        // ---- compute: 8 MFMA per wave
        s16x8 af[4], bfv[2];
        #pragma unroll
        for (int mi = 0; mi < 4; ++mi)
            af[mi] = *(const s16x8*)((const char*)Ash + (((wm>>4) + mi)*1024 + lane*16));
        #pragma unroll
        for (int ni = 0; ni < 2; ++ni)
            bfv[ni] = *(const s16x8*)((const char*)Bsh + (((wn>>4) + ni)*1024 + lane*16));
        #pragma unroll
        for (int mi = 0; mi < 4; ++mi)
            #pragma unroll
            for (int ni = 0; ni < 2; ++ni)
                acc[mi][ni] = __builtin_amdgcn_mfma_f32_16x16x32_bf16(af[mi], bfv[ni], acc[mi][ni], 0, 0, 0);
    }

    unsigned short* out = Out + (size_t)b * CHW_;
    const int cb = wn + (lane & 15);
    const int r0 = (lane >> 4) * 4;
    #pragma unroll
    for (int mi = 0; mi < 4; ++mi)
        #pragma unroll
        for (int j = 0; j < 4; ++j) {
            const int ro = wm + mi*16 + r0 + j;
            const float2 ma = ep[ro];
            const size_t row = (size_t)(mBase + ro)*HW_ + yrow*W_;
            #pragma unroll
            for (int ni = 0; ni < 2; ++ni) {
                const int n = cb + ni*16;
                out[row + n] = f2bf(gelu_exact(fmaf(acc[mi][ni][j], ma.x, ma.y)));
            }
        }
}

// ---------------------------------------------------------------------------
// scores = qt.kt^T/sqrt(HD) per (token,head); softmax over t;
// AW[b,h,t,hw] = sum_s w[b,s]*attn[s,t]    (bf16 QT/KT)
__global__ __launch_bounds__(256)
void attn_scores(const unsigned short* __restrict__ QT, const unsigned short* __restrict__ KT,
                 const float* __restrict__ wsm, float* __restrict__ AW) {
    const int gid = blockIdx.x * 256 + threadIdx.x;
    const int b  = gid >> 12;
    const int hw = gid & (HW_-1);
    const float w0 = wsm[b*3+0], w1 = wsm[b*3+1], w2 = wsm[b*3+2];
    const size_t sStride = (size_t)B_ * CHW_;
    for (int h = 0; h < NH_; ++h) {
        const size_t base = ((size_t)b*C_ + h*HD_)*HW_ + hw;
        float s00=0,s01=0,s02=0,s10=0,s11=0,s12=0,s20=0,s21=0,s22=0;
        #pragma unroll 8
        for (int d = 0; d < HD_; ++d) {
            const size_t off = base + (size_t)d*HW_;
            const float q0 = bf2f(QT[off]), q1 = bf2f(QT[off+sStride]), q2 = bf2f(QT[off+2*sStride]);
            const float k0 = bf2f(KT[off]), k1 = bf2f(KT[off+sStride]), k2 = bf2f(KT[off+2*sStride]);
            s00 = fmaf(q0,k0,s00); s01 = fmaf(q0,k1,s01); s02 = fmaf(q0,k2,s02);
            s10 = fmaf(q1,k0,s10); s11 = fmaf(q1,k1,s11); s12 = fmaf(q1,k2,s12);
            s20 = fmaf(q2,k0,s20); s21 = fmaf(q2,k1,s21); s22 = fmaf(q2,k2,s22);
        }
        const float scl = 0.17677669529663687f;   // 1/sqrt(32)
        float aw0[3], aw1[3], aw2[3];
        {
            float m = fmaxf(fmaxf(s00,s01),s02);
            float e0 = expf(s00*scl - m*scl), e1 = expf(s01*scl - m*scl), e2 = expf(s02*scl - m*scl);
            float inv = 1.f/(e0+e1+e2); aw0[0]=e0*inv; aw0[1]=e1*inv; aw0[2]=e2*inv;
        }
        {
            float m = fmaxf(fmaxf(s10,s11),s12);
            float e0 = expf(s10*scl - m*scl), e1 = expf(s11*scl - m*scl), e2 = expf(s12*scl - m*scl);
            float inv = 1.f/(e0+e1+e2); aw1[0]=e0*inv; aw1[1]=e1*inv; aw1[2]=e2*inv;
        }
        {
            float m = fmaxf(fmaxf(s20,s21),s22);
            float e0 = expf(s20*scl - m*scl), e1 = expf(s21*scl - m*scl), e2 = expf(s22*scl - m*scl);
            float inv = 1.f/(e0+e1+e2); aw2[0]=e0*inv; aw2[1]=e1*inv; aw2[2]=e2*inv;
        }
        #pragma unroll
        for (int t = 0; t < 3; ++t) {
            const float a = w0*aw0[t] + w1*aw1[t] + w2*aw2[t];
            AW[(((size_t)b*NH_ + h)*3 + t)*HW_ + hw] = a;
        }
    }
}

// OM[b,c,hw] = sum_t AW[b,h(c),t,hw] * VT[t,b,c,hw]   (bf16 VT, bf16 OM)
__global__ __launch_bounds__(256)
void om_combine(const unsigned short* __restrict__ VT, const float* __restrict__ AW,
                unsigned short* __restrict__ OM) {
    const int gid = blockIdx.x * 256 + threadIdx.x;
    const int hw = gid & (HW_-1);
    const int c  = (gid >> 12) & (C_-1);
    const int b  = gid >> 20;
    const int h  = c >> 5;
    float r = 0.f;
    #pragma unroll
    for (int t = 0; t < 3; ++t)
        r = fmaf(AW[(((size_t)b*NH_ + h)*3 + t)*HW_ + hw],
                 bf2f(VT[((size_t)(t*B_ + b)*C_ + c)*HW_ + hw]), r);
    OM[gid] = f2bf(r);
}

// ---------------------------------------------------------------------------
extern "C" void kernel_launch(void* const* d_in, const int* in_sizes, int n_in,
                              void* d_out, int out_size, void* d_ws, size_t ws_size,
                              hipStream_t stream) {
    (void)in_sizes; (void)n_in; (void)out_size; (void)ws_size;
    const float* x   = (const float*)d_in[0];
    const float* Wq  = (const float*)d_in[1];
    const float* bq  = (const float*)d_in[2];
    const float* bnq = (const float*)d_in[3];
    const float* Wk  = (const float*)d_in[4];
    const float* bk  = (const float*)d_in[5];
    const float* bnk = (const float*)d_in[6];
    const float* Wv  = (const float*)d_in[7];
    const float* bv  = (const float*)d_in[8];
    const float* bnv = (const float*)d_in[9];
    const float* iw1 = (const float*)d_in[10];
    const float* ib1 = (const float*)d_in[11];
    const float* iw2 = (const float*)d_in[12];
    const float* ib2 = (const float*)d_in[13];
    const float* aiw = (const float*)d_in[14];
    const float* aib = (const float*)d_in[15];
    const float* aow = (const float*)d_in[16];
    const float* aob = (const float*)d_in[17];
    const float* cw  = (const float*)d_in[18];
    const float* cb  = (const float*)d_in[19];
    const float* cbn = (const float*)d_in[20];
    const float* fw2 = (const float*)d_in[21];
    const float* fb2 = (const float*)d_in[22];

    char* wsb = (char*)d_ws;
    unsigned short* xb   = (unsigned short*)(wsb + O_XB);
    unsigned short* s0b  = (unsigned short*)(wsb + O_S0B);
    unsigned short* bufA = (unsigned short*)(wsb + O_BUFA);
    unsigned short* bufB = (unsigned short*)(wsb + O_BUFB);
    unsigned short* OMb  = (unsigned short*)(wsb + O_OMB);
    unsigned short* INTb = (unsigned short*)(wsb + O_INTB);
    unsigned short* CVb  = (unsigned short*)(wsb + O_CVB);
    float* aw_buf        = (float*)(wsb + O_AW);
    unsigned short* WB   = (unsigned short*)(wsb + O_WB);
    float* pooled        = (float*)(wsb + O_POOL);
    float* hbuf          = (float*)(wsb + O_H);
    float* wsm           = (float*)(wsb + O_WSM);
    float* out           = (float*)d_out;

    const unsigned short* Wqb  = WB + WO_WQ;
    const unsigned short* Wkb  = WB + WO_WK;
    const unsigned short* Wvb  = WB + WO_WV;
    const unsigned short* aiwb = WB + WO_AIW;
    const unsigned short* aowb = WB + WO_AOW;
    const unsigned short* cwb  = WB + WO_CW;
    const unsigned short* fw2b = WB + WO_FW2;

    // weight + input casts, importance weights
    cast_w<<<dim3(368), 256, 0, stream>>>(Wq, Wk, Wv, aiw, aow, cw, fw2, WB);
    cast_pool<<<dim3(S_*B_*C_), 256, 0, stream>>>(x, xb, pooled);
    imp1<<<dim3(C_), 256, 0, stream>>>(pooled, iw1, ib1, hbuf);
    imp2<<<dim3(1), 256, 0, stream>>>(hbuf, iw2, ib2, wsm);

    const dim3 g12(HW_/128, C_/128, S_*B_);
    const dim3 g4 (HW_/128, C_/128, B_);
    const dim3 gc (H_, C_/128, B_);

    // Q path
    mgemm<0><<<g12, 256, 0, stream>>>(xb, Wqb, bq, bnq, nullptr, s0b, 1);
    mgemm<1><<<g12, 256, 0, stream>>>(s0b, aiwb, aib, nullptr, nullptr, bufA, 0);
    // K path
    mgemm<0><<<g12, 256, 0, stream>>>(xb, Wkb, bk, bnk, nullptr, s0b, 1);
    mgemm<1><<<g12, 256, 0, stream>>>(s0b, aiwb + C_*C_, aib + C_, nullptr, nullptr, bufB, 0);
    // scores + softmax + importance-fold
    attn_scores<<<dim3(B_*HW_/256), 256, 0, stream>>>(bufA, bufB, wsm, aw_buf);
    // V path (VT overwrites bufA)
    mgemm<0><<<g12, 256, 0, stream>>>(xb, Wvb, bv, bnv, nullptr, s0b, 1);
    mgemm<1><<<g12, 256, 0, stream>>>(s0b, aiwb + 2*C_*C_, aib + 2*C_, nullptr, nullptr, bufA, 0);
    // OM = sum_t aw * VT
    om_combine<<<dim3(B_*CHW_/256), 256, 0, stream>>>(bufA, aw_buf, OMb);
    // attn-out projection (importance fold already applied)
    mgemm<1><<<g4, 256, 0, stream>>>(OMb, aowb, aob, nullptr, nullptr, INTb, 0);
    // 3x3 conv + bias + BN + gelu
    conv_mfma<<<gc, 256, 0, stream>>>(INTb, cwb, cb, cbn, CVb);
    // final 1x1 + bias + residual x[1] (fp32 out)
    mgemm<2><<<g4, 256, 0, stream>>>(CVb, fw2b, fb2, nullptr, x + (size_t)B_*CHW_, out, 0);
}

// Round 8
// 413.096 us; speedup vs baseline: 3.0942x; 1.0947x over previous
//
#include <hip/hip_runtime.h>
#include <hip/hip_bf16.h>
#include <math.h>

#define S_ 3
#define B_ 4
#define C_ 256
#define H_ 64
#define W_ 64
#define HW_ 4096
#define CHW_ (C_*HW_)
#define NH_ 8
#define HD_ 32
#define EPS_ 1e-5f
#define K9_ (9*C_)   // 2304

typedef float  f32x4 __attribute__((ext_vector_type(4)));
typedef short  s16x8 __attribute__((ext_vector_type(8)));
typedef unsigned short u16x4 __attribute__((ext_vector_type(4)));

// ---- workspace layout (bytes) -------------------------------------------
static constexpr size_t HALFB  = (size_t)S_*B_*CHW_*2;   // bf16 S*B*C*HW
static constexpr size_t QB     = (size_t)B_*CHW_*2;      // bf16 B*C*HW
static constexpr size_t O_XB   = 0;
static constexpr size_t O_S0B  = HALFB;
static constexpr size_t O_BUFA = 2*HALFB;
static constexpr size_t O_BUFB = 3*HALFB;
static constexpr size_t O_OMB  = 4*HALFB;
static constexpr size_t O_INTB = 4*HALFB + QB;
static constexpr size_t O_CVB  = 4*HALFB + 2*QB;
static constexpr size_t O_AW   = 4*HALFB + 3*QB;                   // float B*NH*3*HW
static constexpr size_t O_WB   = O_AW + (size_t)B_*NH_*3*HW_*4;    // bf16 packed weights
static constexpr size_t WB_ELEMS = 1507328;
static constexpr size_t O_POOL = O_WB + WB_ELEMS*2;
static constexpr size_t O_H    = O_POOL + (size_t)B_*S_*C_*4;
static constexpr size_t O_WSM  = O_H + (size_t)B_*C_*4;
// packed bf16 weight element offsets
static constexpr size_t WO_WQ  = 0;
static constexpr size_t WO_WK  = 196608;
static constexpr size_t WO_WV  = 393216;
static constexpr size_t WO_AIW = 589824;
static constexpr size_t WO_AOW = 786432;
static constexpr size_t WO_CW  = 851968;     // conv weights, TAP-MAJOR [o][tap*256+c]
static constexpr size_t WO_FW2 = 1441792;

__device__ __forceinline__ float gelu_exact(float x) {
    return 0.5f * x * (1.0f + erff(x * 0.70710678118654752440f));
}
__device__ __forceinline__ unsigned short f2bf(float f) {
    union { float f; unsigned u; } x; x.f = f;
    unsigned r = x.u + 0x7FFFu + ((x.u >> 16) & 1u);
    return (unsigned short)(r >> 16);
}
__device__ __forceinline__ float bf2f(unsigned short h) {
    union { unsigned u; float f; } x; x.u = ((unsigned)h) << 16;
    return x.f;
}

// ---------------------------------------------------------------------------
// cast 6 GEMM weight matrices fp32 -> bf16 (layout preserved)
__global__ __launch_bounds__(256)
void cast_w(const float* __restrict__ w0, const float* __restrict__ w1,
            const float* __restrict__ w2, const float* __restrict__ w3,
            const float* __restrict__ w4, const float* __restrict__ w5,
            unsigned short* __restrict__ dst) {
    int blk = blockIdx.x;
    const float* src; size_t base;
    if      (blk < 48)  { src = w0; base = WO_WQ;  }
    else if (blk < 96)  { src = w1; base = WO_WK;  blk -= 48; }
    else if (blk < 144) { src = w2; base = WO_WV;  blk -= 96; }
    else if (blk < 192) { src = w3; base = WO_AIW; blk -= 144; }
    else if (blk < 208) { src = w4; base = WO_AOW; blk -= 192; }
    else                { src = w5; base = WO_FW2; blk -= 208; }
    size_t off = (size_t)blk*4096 + threadIdx.x*4;
    #pragma unroll
    for (int it = 0; it < 4; ++it, off += 1024) {
        float4 v = *(const float4*)&src[off];
        u16x4 h; h[0] = f2bf(v.x); h[1] = f2bf(v.y); h[2] = f2bf(v.z); h[3] = f2bf(v.w);
        *(u16x4*)&dst[base + off] = h;
    }
}

// conv weights: fp32 [o][c][ky][kx] -> bf16 TAP-MAJOR [o][tap*256 + c]
__global__ __launch_bounds__(256)
void cast_cw(const float* __restrict__ src, unsigned short* __restrict__ dst) {
    const int o = blockIdx.x;
    const int c = threadIdx.x;
    #pragma unroll
    for (int tap = 0; tap < 9; ++tap)
        dst[(size_t)o*K9_ + tap*C_ + c] = f2bf(src[(size_t)o*K9_ + c*9 + tap]);
}

// ---------------------------------------------------------------------------
// fused: cast x -> bf16 AND pooled[b, s*C+c] = mean_hw x[s,b,c,:,:]
__global__ __launch_bounds__(256)
void cast_pool(const float* __restrict__ x, unsigned short* __restrict__ xb,
               float* __restrict__ pooled) {
    const int blk = blockIdx.x;             // (s*B + b)*C + c
    const int c  = blk & (C_-1);
    const int sb = blk >> 8;
    const int s  = sb >> 2, b = sb & 3;
    const float* p = x + (size_t)blk * HW_;
    unsigned short* q = xb + (size_t)blk * HW_;
    float sum = 0.f;
    int i = threadIdx.x * 4;
    #pragma unroll
    for (int it = 0; it < 4; ++it, i += 1024) {
        float4 v = *(const float4*)&p[i];
        sum += v.x + v.y + v.z + v.w;
        u16x4 h; h[0] = f2bf(v.x); h[1] = f2bf(v.y); h[2] = f2bf(v.z); h[3] = f2bf(v.w);
        *(u16x4*)&q[i] = h;
    }
    #pragma unroll
    for (int off = 32; off; off >>= 1) sum += __shfl_down(sum, off);
    __shared__ float red[4];
    if ((threadIdx.x & 63) == 0) red[threadIdx.x >> 6] = sum;
    __syncthreads();
    if (threadIdx.x == 0) {
        float t = red[0] + red[1] + red[2] + red[3];
        pooled[b * (S_*C_) + s * C_ + c] = t * (1.0f / HW_);
    }
}

// h[b, o] = gelu(pooled[b,:] . w1[o,:] + b1[o]);   one block per o
__global__ __launch_bounds__(256)
void imp1(const float* __restrict__ pooled, const float* __restrict__ w1,
          const float* __restrict__ b1, float* __restrict__ h) {
    const int o = blockIdx.x;
    const int tid = threadIdx.x;
    float part[4] = {0.f, 0.f, 0.f, 0.f};
    for (int j = tid; j < S_*C_; j += 256) {
        const float wv = w1[o * (S_*C_) + j];
        #pragma unroll
        for (int b = 0; b < 4; ++b) part[b] = fmaf(pooled[b*(S_*C_) + j], wv, part[b]);
    }
    #pragma unroll
    for (int off = 32; off; off >>= 1)
        #pragma unroll
        for (int b = 0; b < 4; ++b) part[b] += __shfl_down(part[b], off);
    __shared__ float red[4][4];
    if ((tid & 63) == 0) {
        #pragma unroll
        for (int b = 0; b < 4; ++b) red[tid >> 6][b] = part[b];
    }
    __syncthreads();
    if (tid < 4) {
        float t = red[0][tid] + red[1][tid] + red[2][tid] + red[3][tid];
        h[tid * C_ + o] = gelu_exact(t + b1[o]);
    }
}

// w[b, s] = softmax_s(h[b,:] . w2[s,:] + b2[s])
__global__ __launch_bounds__(256)
void imp2(const float* __restrict__ h, const float* __restrict__ w2,
          const float* __restrict__ b2, float* __restrict__ wout) {
    __shared__ float hl[B_*C_];
    __shared__ float lg[4][3];
    const int tid = threadIdx.x;
    for (int i = tid; i < B_*C_; i += 256) hl[i] = h[i];
    __syncthreads();
    if (tid < 12) {
        const int b = tid / 3, s = tid % 3;
        float a = b2[s];
        for (int o = 0; o < C_; ++o) a = fmaf(hl[b*C_ + o], w2[s*C_ + o], a);
        lg[b][s] = a;
    }
    __syncthreads();
    if (tid < 4) {
        const float m = fmaxf(fmaxf(lg[tid][0], lg[tid][1]), lg[tid][2]);
        const float e0 = expf(lg[tid][0]-m), e1 = expf(lg[tid][1]-m), e2 = expf(lg[tid][2]-m);
        const float inv = 1.0f / (e0 + e1 + e2);
        wout[tid*3+0] = e0*inv; wout[tid*3+1] = e1*inv; wout[tid*3+2] = e2*inv;
    }
}

// ---------------------------------------------------------------------------
// bf16 MFMA channel GEMM, tile 128x128, BK=64 (2x 32-k halves), 4 waves.
// Slot-linear frag-packed LDS: thread idx stages the full 8-elem fragment at
// byte idx*16 -> sequential stores (2 lanes/bank = conflict-free), and frag
// reads are lane*16 contiguous. T14 prefetch: next tile's global loads issue
// between barrier and MFMA cluster.
// MODE 0: bias+BN+gelu -> bf16;  MODE 1: bias -> bf16;  MODE 2: bias+resid -> fp32.
template<int MODE>
__global__ __launch_bounds__(256)
void mgemm(const unsigned short* __restrict__ In, const unsigned short* __restrict__ Wb,
           const float* __restrict__ bias, const float* __restrict__ bnp,
           const float* __restrict__ resid, void* __restrict__ Out, int perS) {
    __shared__ __align__(16) unsigned short Ash[8192];   // 2 halves x 8 mblk x 64 slots x 8
    __shared__ __align__(16) unsigned short Bsh[8192];
    __shared__ float2 ep[128];

    const int z    = blockIdx.z;
    const int widx = perS ? (z >> 2) : 0;
    const unsigned short* Wm = Wb + (size_t)widx * (C_*C_);
    const unsigned short* in = In + (size_t)z * CHW_;
    const int tid  = threadIdx.x;
    const int lane = tid & 63;
    const int wid  = tid >> 6;
    const int nBase = blockIdx.x * 128;
    const int mBase = blockIdx.y * 128;
    const int wm = (wid >> 1) * 64;
    const int wn = (wid & 1) * 64;

    if (tid < 128) {
        const int o = mBase + tid;
        float mulc = 1.f, addc = bias[widx*C_ + o];
        if constexpr (MODE == 0) {
            const float g  = bnp[(size_t)widx*4*C_ + o];
            const float be = bnp[(size_t)widx*4*C_ + C_   + o];
            const float mu = bnp[(size_t)widx*4*C_ + 2*C_ + o];
            const float va = bnp[(size_t)widx*4*C_ + 3*C_ + o];
            mulc = g * rsqrtf(va + EPS_);
            addc = (addc - mu) * mulc + be;
        }
        ep[tid] = make_float2(mulc, addc);
    }

    s16x8 ar[4], br[4];
    auto LOADA = [&](int k0) {
        #pragma unroll
        for (int it = 0; it < 4; ++it) {
            const int idx = tid + it*256;          // 0..1023
            const int h = idx >> 9, r = idx & 511;
            const int m = ((r >> 6) << 4) + (r & 15), p = (r & 63) >> 4;
            ar[it] = *(const s16x8*)&Wm[(size_t)(mBase + m)*C_ + k0 + h*32 + 8*p];
        }
    };
    auto LOADB = [&](int k0) {
        #pragma unroll
        for (int it = 0; it < 4; ++it) {
            const int idx = tid + it*256;
            const int h = idx >> 9, r = idx & 511;
            const int n = ((r >> 6) << 4) + (r & 15), p = (r & 63) >> 4;
            const size_t gb = (size_t)(k0 + h*32 + 8*p)*HW_ + nBase + n;
            s16x8 v;
            #pragma unroll
            for (int j = 0; j < 8; ++j) v[j] = (short)in[gb + (size_t)j*HW_];
            br[it] = v;
        }
    };

    const f32x4 zero = {0.f, 0.f, 0.f, 0.f};
    f32x4 acc[4][4];
    #pragma unroll
    for (int i = 0; i < 4; ++i)
        #pragma unroll
        for (int j = 0; j < 4; ++j) acc[i][j] = zero;

    LOADA(0); LOADB(0);
    for (int k0 = 0; k0 < C_; k0 += 64) {
        #pragma unroll
        for (int it = 0; it < 4; ++it) {           // sequential 16B stores
            *(s16x8*)((char*)Ash + (tid + it*256)*16) = ar[it];
            *(s16x8*)((char*)Bsh + (tid + it*256)*16) = br[it];
        }
        __syncthreads();
        if (k0 + 64 < C_) { LOADA(k0 + 64); LOADB(k0 + 64); }   // T14 prefetch
        #pragma unroll
        for (int h = 0; h < 2; ++h) {
            s16x8 af[4], bfv[4];
            #pragma unroll
            for (int mi = 0; mi < 4; ++mi)
                af[mi] = *(const s16x8*)((const char*)Ash + h*8192 + ((wm>>4) + mi)*1024 + lane*16);
            #pragma unroll
            for (int ni = 0; ni < 4; ++ni)
                bfv[ni] = *(const s16x8*)((const char*)Bsh + h*8192 + ((wn>>4) + ni)*1024 + lane*16);
            #pragma unroll
            for (int mi = 0; mi < 4; ++mi)
                #pragma unroll
                for (int ni = 0; ni < 4; ++ni)
                    acc[mi][ni] = __builtin_amdgcn_mfma_f32_16x16x32_bf16(af[mi], bfv[ni], acc[mi][ni], 0, 0, 0);
        }
        __syncthreads();
    }

    const int cb = wn + (lane & 15);
    const int r0 = (lane >> 4) * 4;
    if constexpr (MODE == 2) {
        float* out = (float*)Out + (size_t)z * CHW_;
        const float* rs = resid + (size_t)z * CHW_;
        #pragma unroll
        for (int mi = 0; mi < 4; ++mi)
            #pragma unroll
            for (int j = 0; j < 4; ++j) {
                const int ro = wm + mi*16 + r0 + j;
                const float2 ma = ep[ro];
                const size_t row = (size_t)(mBase + ro)*HW_ + nBase;
                #pragma unroll
                for (int ni = 0; ni < 4; ++ni) {
                    const int n = cb + ni*16;
                    out[row + n] = fmaf(acc[mi][ni][j], ma.x, ma.y) + rs[row + n];
                }
            }
    } else {
        unsigned short* out = (unsigned short*)Out + (size_t)z * CHW_;
        #pragma unroll
        for (int mi = 0; mi < 4; ++mi)
            #pragma unroll
            for (int j = 0; j < 4; ++j) {
                const int ro = wm + mi*16 + r0 + j;
                const float2 ma = ep[ro];
                const size_t row = (size_t)(mBase + ro)*HW_ + nBase;
                #pragma unroll
                for (int ni = 0; ni < 4; ++ni) {
                    const int n = cb + ni*16;
                    float v = fmaf(acc[mi][ni][j], ma.x, ma.y);
                    if constexpr (MODE == 0) v = gelu_exact(v);
                    out[row + n] = f2bf(v);
                }
            }
    }
}

// ---------------------------------------------------------------------------
// 3x3 SAME conv as bf16 MFMA GEMM with TAP-MAJOR flat K (k = tap*256 + c).
// Tap uniform per BK=64 step (64 | 256): masking = 1 scalar row test + per-n
// edge test. Tile 128(o) x 64(n = one image row), 4 waves, same slot-linear
// LDS scheme + T14 prefetch as mgemm. + bias + BN + gelu -> bf16.
__global__ __launch_bounds__(256)
void conv_mfma(const unsigned short* __restrict__ In, const unsigned short* __restrict__ Wc,
               const float* __restrict__ bias, const float* __restrict__ bnp,
               unsigned short* __restrict__ Out) {
    __shared__ __align__(16) unsigned short Ash[8192];   // 128m x 64k
    __shared__ __align__(16) unsigned short Bsh[4096];   // 64k x 64n
    __shared__ float2 ep[128];

    const int b = blockIdx.z;
    const unsigned short* in = In + (size_t)b * CHW_;
    const int tid  = threadIdx.x;
    const int lane = tid & 63;
    const int wid  = tid >> 6;
    const int yrow  = blockIdx.x;          // image row (n-tile)
    const int mBase = blockIdx.y * 128;
    const int wm = (wid >> 1) * 64;
    const int wn = (wid & 1) * 32;

    if (tid < 128) {
        const int o = mBase + tid;
        const float g  = bnp[o];
        const float be = bnp[C_   + o];
        const float mu = bnp[2*C_ + o];
        const float va = bnp[3*C_ + o];
        const float mulc = g * rsqrtf(va + EPS_);
        ep[tid] = make_float2(mulc, (bias[o] - mu) * mulc + be);
    }

    s16x8 ar[4], br[2];
    auto LOADA = [&](int k0) {
        #pragma unroll
        for (int it = 0; it < 4; ++it) {
            const int idx = tid + it*256;          // 0..1023
            const int h = idx >> 9, r = idx & 511;
            const int m = ((r >> 6) << 4) + (r & 15), p = (r & 63) >> 4;
            ar[it] = *(const s16x8*)&Wc[(size_t)(mBase + m)*K9_ + k0 + h*32 + 8*p];
        }
    };
    auto LOADB = [&](int k0) {
        const int tap = k0 >> 8;
        const int c0  = k0 & 255;
        const int t3  = tap / 3;
        const int dy  = t3 - 1;
        const int dx  = tap - t3*3 - 1;
        const int sy  = yrow + dy;
        const bool rowOK = (unsigned)sy < (unsigned)H_;
        #pragma unroll
        for (int it = 0; it < 2; ++it) {
            const int idx = tid + it*256;          // 0..511
            const int h = idx >> 8, r = idx & 255;
            const int n = ((r >> 6) << 4) + (r & 15), p = (r & 63) >> 4;
            const int sx = n + dx;
            s16x8 v = {0,0,0,0,0,0,0,0};
            if (rowOK && (unsigned)sx < (unsigned)W_) {
                const size_t gb = (size_t)(c0 + h*32 + 8*p)*HW_ + sy*W_ + sx;
                #pragma unroll
                for (int j = 0; j < 8; ++j) v[j] = (short)in[gb + (size_t)j*HW_];
            }
            br[it] = v;
        }
    };

    const f32x4 zero = {0.f, 0.f, 0.f, 0.f};
    f32x4 acc[4][2];
    #pragma unroll
    for (int i = 0; i < 4; ++i) { acc[i][0] = zero; acc[i][1] = zero; }

    LOADA(0); LOADB(0);
    for (int k0 = 0; k0 < K9_; k0 += 64) {
        #pragma unroll
        for (int it = 0; it < 4; ++it)
            *(s16x8*)((char*)Ash + (tid + it*256)*16) = ar[it];
        #pragma unroll
        for (int it = 0; it < 2; ++it)
            *(s16x8*)((char*)Bsh + (tid + it*256)*16) = br[it];
        __syncthreads();
        if (k0 + 64 < K9_) { LOADA(k0 + 64); LOADB(k0 + 64); }   // T14 prefetch
        #pragma unroll
        for (int h = 0; h < 2; ++h) {
            s16x8 af[4], bfv[2];
            #pragma unroll
            for (int mi = 0; mi < 4; ++mi)
                af[mi] = *(const s16x8*)((const char*)Ash + h*8192 + ((wm>>4) + mi)*1024 + lane*16);
            #pragma unroll
            for (int ni = 0; ni < 2; ++ni)
                bfv[ni] = *(const s16x8*)((const char*)Bsh + h*4096 + ((wn>>4) + ni)*1024 + lane*16);
            #pragma unroll
            for (int mi = 0; mi < 4; ++mi)
                #pragma unroll
                for (int ni = 0; ni < 2; ++ni)
                    acc[mi][ni] = __builtin_amdgcn_mfma_f32_16x16x32_bf16(af[mi], bfv[ni], acc[mi][ni], 0, 0, 0);
        }
        __syncthreads();
    }

    unsigned short* out = Out + (size_t)b * CHW_;
    const int cb = wn + (lane & 15);
    const int r0 = (lane >> 4) * 4;
    #pragma unroll
    for (int mi = 0; mi < 4; ++mi)
        #pragma unroll
        for (int j = 0; j < 4; ++j) {
            const int ro = wm + mi*16 + r0 + j;
            const float2 ma = ep[ro];
            const size_t row = (size_t)(mBase + ro)*HW_ + yrow*W_;
            #pragma unroll
            for (int ni = 0; ni < 2; ++ni) {
                const int n = cb + ni*16;
                out[row + n] = f2bf(gelu_exact(fmaf(acc[mi][ni][j], ma.x, ma.y)));
            }
        }
}

// ---------------------------------------------------------------------------
// scores = qt.kt^T/sqrt(HD) per (token,head); softmax over t;
// AW[b,h,t,hw] = sum_s w[b,s]*attn[s,t]    (bf16 QT/KT)
__global__ __launch_bounds__(256)
void attn_scores(const unsigned short* __restrict__ QT, const unsigned short* __restrict__ KT,
                 const float* __restrict__ wsm, float* __restrict__ AW) {
    const int gid = blockIdx.x * 256 + threadIdx.x;
    const int b  = gid >> 12;
    const int hw = gid & (HW_-1);
    const float w0 = wsm[b*3+0], w1 = wsm[b*3+1], w2 = wsm[b*3+2];
    const size_t sStride = (size_t)B_ * CHW_;
    for (int h = 0; h < NH_; ++h) {
        const size_t base = ((size_t)b*C_ + h*HD_)*HW_ + hw;
        float s00=0,s01=0,s02=0,s10=0,s11=0,s12=0,s20=0,s21=0,s22=0;
        #pragma unroll 8
        for (int d = 0; d < HD_; ++d) {
            const size_t off = base + (size_t)d*HW_;
            const float q0 = bf2f(QT[off]), q1 = bf2f(QT[off+sStride]), q2 = bf2f(QT[off+2*sStride]);
            const float k0 = bf2f(KT[off]), k1 = bf2f(KT[off+sStride]), k2 = bf2f(KT[off+2*sStride]);
            s00 = fmaf(q0,k0,s00); s01 = fmaf(q0,k1,s01); s02 = fmaf(q0,k2,s02);
            s10 = fmaf(q1,k0,s10); s11 = fmaf(q1,k1,s11); s12 = fmaf(q1,k2,s12);
            s20 = fmaf(q2,k0,s20); s21 = fmaf(q2,k1,s21); s22 = fmaf(q2,k2,s22);
        }
        const float scl = 0.17677669529663687f;   // 1/sqrt(32)
        float aw0[3], aw1[3], aw2[3];
        {
            float m = fmaxf(fmaxf(s00,s01),s02);
            float e0 = expf(s00*scl - m*scl), e1 = expf(s01*scl - m*scl), e2 = expf(s02*scl - m*scl);
            float inv = 1.f/(e0+e1+e2); aw0[0]=e0*inv; aw0[1]=e1*inv; aw0[2]=e2*inv;
        }
        {
            float m = fmaxf(fmaxf(s10,s11),s12);
            float e0 = expf(s10*scl - m*scl), e1 = expf(s11*scl - m*scl), e2 = expf(s12*scl - m*scl);
            float inv = 1.f/(e0+e1+e2); aw1[0]=e0*inv; aw1[1]=e1*inv; aw1[2]=e2*inv;
        }
        {
            float m = fmaxf(fmaxf(s20,s21),s22);
            float e0 = expf(s20*scl - m*scl), e1 = expf(s21*scl - m*scl), e2 = expf(s22*scl - m*scl);
            float inv = 1.f/(e0+e1+e2); aw2[0]=e0*inv; aw2[1]=e1*inv; aw2[2]=e2*inv;
        }
        #pragma unroll
        for (int t = 0; t < 3; ++t) {
            const float a = w0*aw0[t] + w1*aw1[t] + w2*aw2[t];
            AW[(((size_t)b*NH_ + h)*3 + t)*HW_ + hw] = a;
        }
    }
}

// OM[b,c,hw] = sum_t AW[b,h(c),t,hw] * VT[t,b,c,hw]   (bf16 VT, bf16 OM)
__global__ __launch_bounds__(256)
void om_combine(const unsigned short* __restrict__ VT, const float* __restrict__ AW,
                unsigned short* __restrict__ OM) {
    const int gid = blockIdx.x * 256 + threadIdx.x;
    const int hw = gid & (HW_-1);
    const int c  = (gid >> 12) & (C_-1);
    const int b  = gid >> 20;
    const int h  = c >> 5;
    float r = 0.f;
    #pragma unroll
    for (int t = 0; t < 3; ++t)
        r = fmaf(AW[(((size_t)b*NH_ + h)*3 + t)*HW_ + hw],
                 bf2f(VT[((size_t)(t*B_ + b)*C_ + c)*HW_ + hw]), r);
    OM[gid] = f2bf(r);
}

// ---------------------------------------------------------------------------
extern "C" void kernel_launch(void* const* d_in, const int* in_sizes, int n_in,
                              void* d_out, int out_size, void* d_ws, size_t ws_size,
                              hipStream_t stream) {
    (void)in_sizes; (void)n_in; (void)out_size; (void)ws_size;
    const float* x   = (const float*)d_in[0];
    const float* Wq  = (const float*)d_in[1];
    const float* bq  = (const float*)d_in[2];
    const float* bnq = (const float*)d_in[3];
    const float* Wk  = (const float*)d_in[4];
    const float* bk  = (const float*)d_in[5];
    const float* bnk = (const float*)d_in[6];
    const float* Wv  = (const float*)d_in[7];
    const float* bv  = (const float*)d_in[8];
    const float* bnv = (const float*)d_in[9];
    const float* iw1 = (const float*)d_in[10];
    const float* ib1 = (const float*)d_in[11];
    const float* iw2 = (const float*)d_in[12];
    const float* ib2 = (const float*)d_in[13];
    const float* aiw = (const float*)d_in[14];
    const float* aib = (const float*)d_in[15];
    const float* aow = (const float*)d_in[16];
    const float* aob = (const float*)d_in[17];
    const float* cw  = (const float*)d_in[18];
    const float* cb  = (const float*)d_in[19];
    const float* cbn = (const float*)d_in[20];
    const float* fw2 = (const float*)d_in[21];
    const float* fb2 = (const float*)d_in[22];

    char* wsb = (char*)d_ws;
    unsigned short* xb   = (unsigned short*)(wsb + O_XB);
    unsigned short* s0b  = (unsigned short*)(wsb + O_S0B);
    unsigned short* bufA = (unsigned short*)(wsb + O_BUFA);
    unsigned short* bufB = (unsigned short*)(wsb + O_BUFB);
    unsigned short* OMb  = (unsigned short*)(wsb + O_OMB);
    unsigned short* INTb = (unsigned short*)(wsb + O_INTB);
    unsigned short* CVb  = (unsigned short*)(wsb + O_CVB);
    float* aw_buf        = (float*)(wsb + O_AW);
    unsigned short* WB   = (unsigned short*)(wsb + O_WB);
    float* pooled        = (float*)(wsb + O_POOL);
    float* hbuf          = (float*)(wsb + O_H);
    float* wsm           = (float*)(wsb + O_WSM);
    float* out           = (float*)d_out;

    const unsigned short* Wqb  = WB + WO_WQ;
    const unsigned short* Wkb  = WB + WO_WK;
    const unsigned short* Wvb  = WB + WO_WV;
    const unsigned short* aiwb = WB + WO_AIW;
    const unsigned short* aowb = WB + WO_AOW;
    const unsigned short* cwb  = WB + WO_CW;
    const unsigned short* fw2b = WB + WO_FW2;

    // weight + input casts (cast_cw permutes conv weights to tap-major)
    cast_w<<<dim3(224), 256, 0, stream>>>(Wq, Wk, Wv, aiw, aow, fw2, WB);
    cast_cw<<<dim3(256), 256, 0, stream>>>(cw, (unsigned short*)(WB + WO_CW));
    cast_pool<<<dim3(S_*B_*C_), 256, 0, stream>>>(x, xb, pooled);
    imp1<<<dim3(C_), 256, 0, stream>>>(pooled, iw1, ib1, hbuf);
    imp2<<<dim3(1), 256, 0, stream>>>(hbuf, iw2, ib2, wsm);

    const dim3 g12(HW_/128, C_/128, S_*B_);
    const dim3 g4 (HW_/128, C_/128, B_);
    const dim3 gc (H_, C_/128, B_);

    // Q path
    mgemm<0><<<g12, 256, 0, stream>>>(xb, Wqb, bq, bnq, nullptr, s0b, 1);
    mgemm<1><<<g12, 256, 0, stream>>>(s0b, aiwb, aib, nullptr, nullptr, bufA, 0);
    // K path
    mgemm<0><<<g12, 256, 0, stream>>>(xb, Wkb, bk, bnk, nullptr, s0b, 1);
    mgemm<1><<<g12, 256, 0, stream>>>(s0b, aiwb + C_*C_, aib + C_, nullptr, nullptr, bufB, 0);
    // scores + softmax + importance-fold
    attn_scores<<<dim3(B_*HW_/256), 256, 0, stream>>>(bufA, bufB, wsm, aw_buf);
    // V path (VT overwrites bufA)
    mgemm<0><<<g12, 256, 0, stream>>>(xb, Wvb, bv, bnv, nullptr, s0b, 1);
    mgemm<1><<<g12, 256, 0, stream>>>(s0b, aiwb + 2*C_*C_, aib + 2*C_, nullptr, nullptr, bufA, 0);
    // OM = sum_t aw * VT
    om_combine<<<dim3(B_*CHW_/256), 256, 0, stream>>>(bufA, aw_buf, OMb);
    // attn-out projection (importance fold already applied)
    mgemm<1><<<g4, 256, 0, stream>>>(OMb, aowb, aob, nullptr, nullptr, INTb, 0);
    // 3x3 conv + bias + BN + gelu (tap-major flat-K MFMA)
    conv_mfma<<<gc, 256, 0, stream>>>(INTb, cwb, cb, cbn, CVb);
    // final 1x1 + bias + residual x[1] (fp32 out)
    mgemm<2><<<g4, 256, 0, stream>>>(CVb, fw2b, fb2, nullptr, x + (size_t)B_*CHW_, out, 0);
}

// Round 9
// 380.981 us; speedup vs baseline: 3.3551x; 1.0843x over previous
//
#include <hip/hip_runtime.h>
#include <hip/hip_bf16.h>
#include <math.h>

#define S_ 3
#define B_ 4
#define C_ 256
#define H_ 64
#define W_ 64
#define HW_ 4096
#define CHW_ (C_*HW_)
#define NH_ 8
#define HD_ 32
#define EPS_ 1e-5f
#define K9_ (9*C_)   // 2304

typedef float  f32x4 __attribute__((ext_vector_type(4)));
typedef short  s16x8 __attribute__((ext_vector_type(8)));
typedef unsigned short u16x4 __attribute__((ext_vector_type(4)));
typedef unsigned short u16x8 __attribute__((ext_vector_type(8)));
typedef unsigned int   u32x2 __attribute__((ext_vector_type(2)));

// ---- workspace layout (bytes) -------------------------------------------
static constexpr size_t HALFB  = (size_t)S_*B_*CHW_*2;   // bf16 S*B*C*HW
static constexpr size_t QB     = (size_t)B_*CHW_*2;      // bf16 B*C*HW
static constexpr size_t O_XB   = 0;
static constexpr size_t O_S0B  = HALFB;
static constexpr size_t O_BUFA = 2*HALFB;
static constexpr size_t O_BUFB = 3*HALFB;
static constexpr size_t O_OMB  = 4*HALFB;
static constexpr size_t O_INTB = 4*HALFB + QB;
static constexpr size_t O_CVB  = 4*HALFB + 2*QB;
static constexpr size_t O_AW   = 4*HALFB + 3*QB;                   // float B*NH*3*HW
static constexpr size_t O_WB   = O_AW + (size_t)B_*NH_*3*HW_*4;    // bf16 packed weights
static constexpr size_t WB_ELEMS = 1507328;
static constexpr size_t O_POOL = O_WB + WB_ELEMS*2;
static constexpr size_t O_H    = O_POOL + (size_t)B_*S_*C_*4;
static constexpr size_t O_WSM  = O_H + (size_t)B_*C_*4;
// packed bf16 weight element offsets
static constexpr size_t WO_WQ  = 0;
static constexpr size_t WO_WK  = 196608;
static constexpr size_t WO_WV  = 393216;
static constexpr size_t WO_AIW = 589824;
static constexpr size_t WO_AOW = 786432;
static constexpr size_t WO_CW  = 851968;     // conv weights, TAP-MAJOR [o][tap*256+c]
static constexpr size_t WO_FW2 = 1441792;

__device__ __forceinline__ float gelu_exact(float x) {
    return 0.5f * x * (1.0f + erff(x * 0.70710678118654752440f));
}
__device__ __forceinline__ unsigned short f2bf(float f) {
    union { float f; unsigned u; } x; x.f = f;
    unsigned r = x.u + 0x7FFFu + ((x.u >> 16) & 1u);
    return (unsigned short)(r >> 16);
}
__device__ __forceinline__ float bf2f(unsigned short h) {
    union { unsigned u; float f; } x; x.u = ((unsigned)h) << 16;
    return x.f;
}

// ---------------------------------------------------------------------------
// cast 6 GEMM weight matrices fp32 -> bf16 (layout preserved)
__global__ __launch_bounds__(256)
void cast_w(const float* __restrict__ w0, const float* __restrict__ w1,
            const float* __restrict__ w2, const float* __restrict__ w3,
            const float* __restrict__ w4, const float* __restrict__ w5,
            unsigned short* __restrict__ dst) {
    int blk = blockIdx.x;
    const float* src; size_t base;
    if      (blk < 48)  { src = w0; base = WO_WQ;  }
    else if (blk < 96)  { src = w1; base = WO_WK;  blk -= 48; }
    else if (blk < 144) { src = w2; base = WO_WV;  blk -= 96; }
    else if (blk < 192) { src = w3; base = WO_AIW; blk -= 144; }
    else if (blk < 208) { src = w4; base = WO_AOW; blk -= 192; }
    else                { src = w5; base = WO_FW2; blk -= 208; }
    size_t off = (size_t)blk*4096 + threadIdx.x*4;
    #pragma unroll
    for (int it = 0; it < 4; ++it, off += 1024) {
        float4 v = *(const float4*)&src[off];
        u16x4 h; h[0] = f2bf(v.x); h[1] = f2bf(v.y); h[2] = f2bf(v.z); h[3] = f2bf(v.w);
        *(u16x4*)&dst[base + off] = h;
    }
}

// conv weights: fp32 [o][c][ky][kx] -> bf16 TAP-MAJOR [o][tap*256 + c]
__global__ __launch_bounds__(256)
void cast_cw(const float* __restrict__ src, unsigned short* __restrict__ dst) {
    const int o = blockIdx.x;
    const int c = threadIdx.x;
    #pragma unroll
    for (int tap = 0; tap < 9; ++tap)
        dst[(size_t)o*K9_ + tap*C_ + c] = f2bf(src[(size_t)o*K9_ + c*9 + tap]);
}

// ---------------------------------------------------------------------------
// fused: cast x -> bf16 AND pooled[b, s*C+c] = mean_hw x[s,b,c,:,:]
__global__ __launch_bounds__(256)
void cast_pool(const float* __restrict__ x, unsigned short* __restrict__ xb,
               float* __restrict__ pooled) {
    const int blk = blockIdx.x;             // (s*B + b)*C + c
    const int c  = blk & (C_-1);
    const int sb = blk >> 8;
    const int s  = sb >> 2, b = sb & 3;
    const float* p = x + (size_t)blk * HW_;
    unsigned short* q = xb + (size_t)blk * HW_;
    float sum = 0.f;
    int i = threadIdx.x * 4;
    #pragma unroll
    for (int it = 0; it < 4; ++it, i += 1024) {
        float4 v = *(const float4*)&p[i];
        sum += v.x + v.y + v.z + v.w;
        u16x4 h; h[0] = f2bf(v.x); h[1] = f2bf(v.y); h[2] = f2bf(v.z); h[3] = f2bf(v.w);
        *(u16x4*)&q[i] = h;
    }
    #pragma unroll
    for (int off = 32; off; off >>= 1) sum += __shfl_down(sum, off);
    __shared__ float red[4];
    if ((threadIdx.x & 63) == 0) red[threadIdx.x >> 6] = sum;
    __syncthreads();
    if (threadIdx.x == 0) {
        float t = red[0] + red[1] + red[2] + red[3];
        pooled[b * (S_*C_) + s * C_ + c] = t * (1.0f / HW_);
    }
}

// h[b, o] = gelu(pooled[b,:] . w1[o,:] + b1[o]);   one block per o
__global__ __launch_bounds__(256)
void imp1(const float* __restrict__ pooled, const float* __restrict__ w1,
          const float* __restrict__ b1, float* __restrict__ h) {
    const int o = blockIdx.x;
    const int tid = threadIdx.x;
    float part[4] = {0.f, 0.f, 0.f, 0.f};
    for (int j = tid; j < S_*C_; j += 256) {
        const float wv = w1[o * (S_*C_) + j];
        #pragma unroll
        for (int b = 0; b < 4; ++b) part[b] = fmaf(pooled[b*(S_*C_) + j], wv, part[b]);
    }
    #pragma unroll
    for (int off = 32; off; off >>= 1)
        #pragma unroll
        for (int b = 0; b < 4; ++b) part[b] += __shfl_down(part[b], off);
    __shared__ float red[4][4];
    if ((tid & 63) == 0) {
        #pragma unroll
        for (int b = 0; b < 4; ++b) red[tid >> 6][b] = part[b];
    }
    __syncthreads();
    if (tid < 4) {
        float t = red[0][tid] + red[1][tid] + red[2][tid] + red[3][tid];
        h[tid * C_ + o] = gelu_exact(t + b1[o]);
    }
}

// w[b, s] = softmax_s(h[b,:] . w2[s,:] + b2[s])
__global__ __launch_bounds__(256)
void imp2(const float* __restrict__ h, const float* __restrict__ w2,
          const float* __restrict__ b2, float* __restrict__ wout) {
    __shared__ float hl[B_*C_];
    __shared__ float lg[4][3];
    const int tid = threadIdx.x;
    for (int i = tid; i < B_*C_; i += 256) hl[i] = h[i];
    __syncthreads();
    if (tid < 12) {
        const int b = tid / 3, s = tid % 3;
        float a = b2[s];
        for (int o = 0; o < C_; ++o) a = fmaf(hl[b*C_ + o], w2[s*C_ + o], a);
        lg[b][s] = a;
    }
    __syncthreads();
    if (tid < 4) {
        const float m = fmaxf(fmaxf(lg[tid][0], lg[tid][1]), lg[tid][2]);
        const float e0 = expf(lg[tid][0]-m), e1 = expf(lg[tid][1]-m), e2 = expf(lg[tid][2]-m);
        const float inv = 1.0f / (e0 + e1 + e2);
        wout[tid*3+0] = e0*inv; wout[tid*3+1] = e1*inv; wout[tid*3+2] = e2*inv;
    }
}

// ---------------------------------------------------------------------------
// bf16 MFMA channel GEMM, tile 128x128, BK=64 (2x 32-k halves), 4 waves.
// A: slot-linear frag-packed LDS (16B stores/reads, conflict-free).
// B: coalesced dwordx4 global loads (4k x 8n per thread) + in-register 4x8
//    transpose + 8x ds_write_b64 into frag-packed layout XOR-swizzled by
//    (nblk&7)<<4 (writer ~2 lanes/bank; reader applies same uniform XOR ->
//    conflict-free). Replaces 32 scalar global loads per thread per K-step.
// T14 prefetch between barrier and MFMA cluster.
// MODE 0: bias+BN+gelu -> bf16;  MODE 1: bias -> bf16;  MODE 2: bias+resid -> fp32.
template<int MODE>
__global__ __launch_bounds__(256)
void mgemm(const unsigned short* __restrict__ In, const unsigned short* __restrict__ Wb,
           const float* __restrict__ bias, const float* __restrict__ bnp,
           const float* __restrict__ resid, void* __restrict__ Out, int perS) {
    __shared__ __align__(16) unsigned short Ash[8192];   // 2 halves x 8 mblk x 64 slots x 8
    __shared__ __align__(16) unsigned short Bsh[8192];
    __shared__ float2 ep[128];

    const int z    = blockIdx.z;
    const int widx = perS ? (z >> 2) : 0;
    const unsigned short* Wm = Wb + (size_t)widx * (C_*C_);
    const unsigned short* in = In + (size_t)z * CHW_;
    const int tid  = threadIdx.x;
    const int lane = tid & 63;
    const int wid  = tid >> 6;
    const int nBase = blockIdx.x * 128;
    const int mBase = blockIdx.y * 128;
    const int wm = (wid >> 1) * 64;
    const int wn = (wid & 1) * 64;

    if (tid < 128) {
        const int o = mBase + tid;
        float mulc = 1.f, addc = bias[widx*C_ + o];
        if constexpr (MODE == 0) {
            const float g  = bnp[(size_t)widx*4*C_ + o];
            const float be = bnp[(size_t)widx*4*C_ + C_   + o];
            const float mu = bnp[(size_t)widx*4*C_ + 2*C_ + o];
            const float va = bnp[(size_t)widx*4*C_ + 3*C_ + o];
            mulc = g * rsqrtf(va + EPS_);
            addc = (addc - mu) * mulc + be;
        }
        ep[tid] = make_float2(mulc, addc);
    }

    // B-staging geometry: thread = (kb = tid>>4, ng = tid&15) -> 4k x 8n block
    const int kb   = tid >> 4;
    const int ng   = tid & 15;
    const int bh   = kb >> 3;             // half
    const int bp   = (kb & 7) >> 1;       // k-quad-pair within half
    const int blo  = (kb & 1);            // which 8B of the 16B fragment
    const int nblk = ng >> 1;
    const int bpar = (ng & 1);

    s16x8 ar[4];
    u16x8 Lb[4];
    auto LOADA = [&](int k0) {
        #pragma unroll
        for (int it = 0; it < 4; ++it) {
            const int idx = tid + it*256;          // 0..1023
            const int h = idx >> 9, r = idx & 511;
            const int m = ((r >> 6) << 4) + (r & 15), p = (r & 63) >> 4;
            ar[it] = *(const s16x8*)&Wm[(size_t)(mBase + m)*C_ + k0 + h*32 + 8*p];
        }
    };
    auto LOADB = [&](int k0) {
        const size_t gb = (size_t)(k0 + kb*4)*HW_ + nBase + ng*8;
        #pragma unroll
        for (int j = 0; j < 4; ++j)
            Lb[j] = *(const u16x8*)&in[gb + (size_t)j*HW_];
    };
    auto STOREB = [&]() {
        char* base = (char*)Bsh + bh*8192 + nblk*1024 + blo*8;
        #pragma unroll
        for (int i = 0; i < 8; ++i) {
            const int slot = bpar*8 + i + 16*bp;
            u32x2 v;
            v[0] = (unsigned)Lb[0][i] | ((unsigned)Lb[1][i] << 16);
            v[1] = (unsigned)Lb[2][i] | ((unsigned)Lb[3][i] << 16);
            *(u32x2*)(base + ((slot*16) ^ ((nblk & 7) << 4))) = v;
        }
    };

    const f32x4 zero = {0.f, 0.f, 0.f, 0.f};
    f32x4 acc[4][4];
    #pragma unroll
    for (int i = 0; i < 4; ++i)
        #pragma unroll
        for (int j = 0; j < 4; ++j) acc[i][j] = zero;

    LOADA(0); LOADB(0);
    for (int k0 = 0; k0 < C_; k0 += 64) {
        #pragma unroll
        for (int it = 0; it < 4; ++it)             // A: sequential 16B stores
            *(s16x8*)((char*)Ash + (tid + it*256)*16) = ar[it];
        STOREB();
        __syncthreads();
        if (k0 + 64 < C_) { LOADA(k0 + 64); LOADB(k0 + 64); }   // T14 prefetch
        #pragma unroll
        for (int h = 0; h < 2; ++h) {
            s16x8 af[4], bfv[4];
            #pragma unroll
            for (int mi = 0; mi < 4; ++mi)
                af[mi] = *(const s16x8*)((const char*)Ash + h*8192 + ((wm>>4) + mi)*1024 + lane*16);
            #pragma unroll
            for (int ni = 0; ni < 4; ++ni) {
                const int nb = (wn>>4) + ni;
                bfv[ni] = *(const s16x8*)((const char*)Bsh + h*8192 + nb*1024
                                          + ((lane*16) ^ ((nb & 7) << 4)));
            }
            #pragma unroll
            for (int mi = 0; mi < 4; ++mi)
                #pragma unroll
                for (int ni = 0; ni < 4; ++ni)
                    acc[mi][ni] = __builtin_amdgcn_mfma_f32_16x16x32_bf16(af[mi], bfv[ni], acc[mi][ni], 0, 0, 0);
        }
        __syncthreads();
    }

    const int cb = wn + (lane & 15);
    const int r0 = (lane >> 4) * 4;
    if constexpr (MODE == 2) {
        float* out = (float*)Out + (size_t)z * CHW_;
        const float* rs = resid + (size_t)z * CHW_;
        #pragma unroll
        for (int mi = 0; mi < 4; ++mi)
            #pragma unroll
            for (int j = 0; j < 4; ++j) {
                const int ro = wm + mi*16 + r0 + j;
                const float2 ma = ep[ro];
                const size_t row = (size_t)(mBase + ro)*HW_ + nBase;
                #pragma unroll
                for (int ni = 0; ni < 4; ++ni) {
                    const int n = cb + ni*16;
                    out[row + n] = fmaf(acc[mi][ni][j], ma.x, ma.y) + rs[row + n];
                }
            }
    } else {
        unsigned short* out = (unsigned short*)Out + (size_t)z * CHW_;
        #pragma unroll
        for (int mi = 0; mi < 4; ++mi)
            #pragma unroll
            for (int j = 0; j < 4; ++j) {
                const int ro = wm + mi*16 + r0 + j;
                const float2 ma = ep[ro];
                const size_t row = (size_t)(mBase + ro)*HW_ + nBase;
                #pragma unroll
                for (int ni = 0; ni < 4; ++ni) {
                    const int n = cb + ni*16;
                    float v = fmaf(acc[mi][ni][j], ma.x, ma.y);
                    if constexpr (MODE == 0) v = gelu_exact(v);
                    out[row + n] = f2bf(v);
                }
            }
    }
}

// ---------------------------------------------------------------------------
// 3x3 SAME conv as bf16 MFMA GEMM with TAP-MAJOR flat K (k = tap*256 + c).
// Tap uniform per BK=64 step (64 | 256): masking = 1 scalar row test + per-n
// edge test. Tile 128(o) x 64(n = one image row), 4 waves, slot-linear
// LDS scheme + T14 prefetch. + bias + BN + gelu -> bf16. (Unchanged from R8:
// conflicts already 0; edge-shifted loads would be 16B-misaligned if vectorized.)
__global__ __launch_bounds__(256)
void conv_mfma(const unsigned short* __restrict__ In, const unsigned short* __restrict__ Wc,
               const float* __restrict__ bias, const float* __restrict__ bnp,
               unsigned short* __restrict__ Out) {
    __shared__ __align__(16) unsigned short Ash[8192];   // 128m x 64k
    __shared__ __align__(16) unsigned short Bsh[4096];   // 64k x 64n
    __shared__ float2 ep[128];

    const int b = blockIdx.z;
    const unsigned short* in = In + (size_t)b * CHW_;
    const int tid  = threadIdx.x;
    const int lane = tid & 63;
    const int wid  = tid >> 6;
    const int yrow  = blockIdx.x;          // image row (n-tile)
    const int mBase = blockIdx.y * 128;
    const int wm = (wid >> 1) * 64;
    const int wn = (wid & 1) * 32;

    if (tid < 128) {
        const int o = mBase + tid;
        const float g  = bnp[o];
        const float be = bnp[C_   + o];
        const float mu = bnp[2*C_ + o];
        const float va = bnp[3*C_ + o];
        const float mulc = g * rsqrtf(va + EPS_);
        ep[tid] = make_float2(mulc, (bias[o] - mu) * mulc + be);
    }

    s16x8 ar[4], br[2];
    auto LOADA = [&](int k0) {
        #pragma unroll
        for (int it = 0; it < 4; ++it) {
            const int idx = tid + it*256;          // 0..1023
            const int h = idx >> 9, r = idx & 511;
            const int m = ((r >> 6) << 4) + (r & 15), p = (r & 63) >> 4;
            ar[it] = *(const s16x8*)&Wc[(size_t)(mBase + m)*K9_ + k0 + h*32 + 8*p];
        }
    };
    auto LOADB = [&](int k0) {
        const int tap = k0 >> 8;
        const int c0  = k0 & 255;
        const int t3  = tap / 3;
        const int dy  = t3 - 1;
        const int dx  = tap - t3*3 - 1;
        const int sy  = yrow + dy;
        const bool rowOK = (unsigned)sy < (unsigned)H_;
        #pragma unroll
        for (int it = 0; it < 2; ++it) {
            const int idx = tid + it*256;          // 0..511
            const int h = idx >> 8, r = idx & 255;
            const int n = ((r >> 6) << 4) + (r & 15), p = (r & 63) >> 4;
            const int sx = n + dx;
            s16x8 v = {0,0,0,0,0,0,0,0};
            if (rowOK && (unsigned)sx < (unsigned)W_) {
                const size_t gb = (size_t)(c0 + h*32 + 8*p)*HW_ + sy*W_ + sx;
                #pragma unroll
                for (int j = 0; j < 8; ++j) v[j] = (short)in[gb + (size_t)j*HW_];
            }
            br[it] = v;
        }
    };

    const f32x4 zero = {0.f, 0.f, 0.f, 0.f};
    f32x4 acc[4][2];
    #pragma unroll
    for (int i = 0; i < 4; ++i) { acc[i][0] = zero; acc[i][1] = zero; }

    LOADA(0); LOADB(0);
    for (int k0 = 0; k0 < K9_; k0 += 64) {
        #pragma unroll
        for (int it = 0; it < 4; ++it)
            *(s16x8*)((char*)Ash + (tid + it*256)*16) = ar[it];
        #pragma unroll
        for (int it = 0; it < 2; ++it)
            *(s16x8*)((char*)Bsh + (tid + it*256)*16) = br[it];
        __syncthreads();
        if (k0 + 64 < K9_) { LOADA(k0 + 64); LOADB(k0 + 64); }   // T14 prefetch
        #pragma unroll
        for (int h = 0; h < 2; ++h) {
            s16x8 af[4], bfv[2];
            #pragma unroll
            for (int mi = 0; mi < 4; ++mi)
                af[mi] = *(const s16x8*)((const char*)Ash + h*8192 + ((wm>>4) + mi)*1024 + lane*16);
            #pragma unroll
            for (int ni = 0; ni < 2; ++ni)
                bfv[ni] = *(const s16x8*)((const char*)Bsh + h*4096 + ((wn>>4) + ni)*1024 + lane*16);
            #pragma unroll
            for (int mi = 0; mi < 4; ++mi)
                #pragma unroll
                for (int ni = 0; ni < 2; ++ni)
                    acc[mi][ni] = __builtin_amdgcn_mfma_f32_16x16x32_bf16(af[mi], bfv[ni], acc[mi][ni], 0, 0, 0);
        }
        __syncthreads();
    }

    unsigned short* out = Out + (size_t)b * CHW_;
    const int cb = wn + (lane & 15);
    const int r0 = (lane >> 4) * 4;
    #pragma unroll
    for (int mi = 0; mi < 4; ++mi)
        #pragma unroll
        for (int j = 0; j < 4; ++j) {
            const int ro = wm + mi*16 + r0 + j;
            const float2 ma = ep[ro];
            const size_t row = (size_t)(mBase + ro)*HW_ + yrow*W_;
            #pragma unroll
            for (int ni = 0; ni < 2; ++ni) {
                const int n = cb + ni*16;
                out[row + n] = f2bf(gelu_exact(fmaf(acc[mi][ni][j], ma.x, ma.y)));
            }
        }
}

// ---------------------------------------------------------------------------
// scores = qt.kt^T/sqrt(HD) per (token,head); softmax over t;
// AW[b,h,t,hw] = sum_s w[b,s]*attn[s,t]    (bf16 QT/KT)
__global__ __launch_bounds__(256)
void attn_scores(const unsigned short* __restrict__ QT, const unsigned short* __restrict__ KT,
                 const float* __restrict__ wsm, float* __restrict__ AW) {
    const int gid = blockIdx.x * 256 + threadIdx.x;
    const int b  = gid >> 12;
    const int hw = gid & (HW_-1);
    const float w0 = wsm[b*3+0], w1 = wsm[b*3+1], w2 = wsm[b*3+2];
    const size_t sStride = (size_t)B_ * CHW_;
    for (int h = 0; h < NH_; ++h) {
        const size_t base = ((size_t)b*C_ + h*HD_)*HW_ + hw;
        float s00=0,s01=0,s02=0,s10=0,s11=0,s12=0,s20=0,s21=0,s22=0;
        #pragma unroll 8
        for (int d = 0; d < HD_; ++d) {
            const size_t off = base + (size_t)d*HW_;
            const float q0 = bf2f(QT[off]), q1 = bf2f(QT[off+sStride]), q2 = bf2f(QT[off+2*sStride]);
            const float k0 = bf2f(KT[off]), k1 = bf2f(KT[off+sStride]), k2 = bf2f(KT[off+2*sStride]);
            s00 = fmaf(q0,k0,s00); s01 = fmaf(q0,k1,s01); s02 = fmaf(q0,k2,s02);
            s10 = fmaf(q1,k0,s10); s11 = fmaf(q1,k1,s11); s12 = fmaf(q1,k2,s12);
            s20 = fmaf(q2,k0,s20); s21 = fmaf(q2,k1,s21); s22 = fmaf(q2,k2,s22);
        }
        const float scl = 0.17677669529663687f;   // 1/sqrt(32)
        float aw0[3], aw1[3], aw2[3];
        {
            float m = fmaxf(fmaxf(s00,s01),s02);
            float e0 = expf(s00*scl - m*scl), e1 = expf(s01*scl - m*scl), e2 = expf(s02*scl - m*scl);
            float inv = 1.f/(e0+e1+e2); aw0[0]=e0*inv; aw0[1]=e1*inv; aw0[2]=e2*inv;
        }
        {
            float m = fmaxf(fmaxf(s10,s11),s12);
            float e0 = expf(s10*scl - m*scl), e1 = expf(s11*scl - m*scl), e2 = expf(s12*scl - m*scl);
            float inv = 1.f/(e0+e1+e2); aw1[0]=e0*inv; aw1[1]=e1*inv; aw1[2]=e2*inv;
        }
        {
            float m = fmaxf(fmaxf(s20,s21),s22);
            float e0 = expf(s20*scl - m*scl), e1 = expf(s21*scl - m*scl), e2 = expf(s22*scl - m*scl);
            float inv = 1.f/(e0+e1+e2); aw2[0]=e0*inv; aw2[1]=e1*inv; aw2[2]=e2*inv;
        }
        #pragma unroll
        for (int t = 0; t < 3; ++t) {
            const float a = w0*aw0[t] + w1*aw1[t] + w2*aw2[t];
            AW[(((size_t)b*NH_ + h)*3 + t)*HW_ + hw] = a;
        }
    }
}

// OM[b,c,hw] = sum_t AW[b,h(c),t,hw] * VT[t,b,c,hw]   (bf16 VT, bf16 OM)
__global__ __launch_bounds__(256)
void om_combine(const unsigned short* __restrict__ VT, const float* __restrict__ AW,
                unsigned short* __restrict__ OM) {
    const int gid = blockIdx.x * 256 + threadIdx.x;
    const int hw = gid & (HW_-1);
    const int c  = (gid >> 12) & (C_-1);
    const int b  = gid >> 20;
    const int h  = c >> 5;
    float r = 0.f;
    #pragma unroll
    for (int t = 0; t < 3; ++t)
        r = fmaf(AW[(((size_t)b*NH_ + h)*3 + t)*HW_ + hw],
                 bf2f(VT[((size_t)(t*B_ + b)*C_ + c)*HW_ + hw]), r);
    OM[gid] = f2bf(r);
}

// ---------------------------------------------------------------------------
extern "C" void kernel_launch(void* const* d_in, const int* in_sizes, int n_in,
                              void* d_out, int out_size, void* d_ws, size_t ws_size,
                              hipStream_t stream) {
    (void)in_sizes; (void)n_in; (void)out_size; (void)ws_size;
    const float* x   = (const float*)d_in[0];
    const float* Wq  = (const float*)d_in[1];
    const float* bq  = (const float*)d_in[2];
    const float* bnq = (const float*)d_in[3];
    const float* Wk  = (const float*)d_in[4];
    const float* bk  = (const float*)d_in[5];
    const float* bnk = (const float*)d_in[6];
    const float* Wv  = (const float*)d_in[7];
    const float* bv  = (const float*)d_in[8];
    const float* bnv = (const float*)d_in[9];
    const float* iw1 = (const float*)d_in[10];
    const float* ib1 = (const float*)d_in[11];
    const float* iw2 = (const float*)d_in[12];
    const float* ib2 = (const float*)d_in[13];
    const float* aiw = (const float*)d_in[14];
    const float* aib = (const float*)d_in[15];
    const float* aow = (const float*)d_in[16];
    const float* aob = (const float*)d_in[17];
    const float* cw  = (const float*)d_in[18];
    const float* cb  = (const float*)d_in[19];
    const float* cbn = (const float*)d_in[20];
    const float* fw2 = (const float*)d_in[21];
    const float* fb2 = (const float*)d_in[22];

    char* wsb = (char*)d_ws;
    unsigned short* xb   = (unsigned short*)(wsb + O_XB);
    unsigned short* s0b  = (unsigned short*)(wsb + O_S0B);
    unsigned short* bufA = (unsigned short*)(wsb + O_BUFA);
    unsigned short* bufB = (unsigned short*)(wsb + O_BUFB);
    unsigned short* OMb  = (unsigned short*)(wsb + O_OMB);
    unsigned short* INTb = (unsigned short*)(wsb + O_INTB);
    unsigned short* CVb  = (unsigned short*)(wsb + O_CVB);
    float* aw_buf        = (float*)(wsb + O_AW);
    unsigned short* WB   = (unsigned short*)(wsb + O_WB);
    float* pooled        = (float*)(wsb + O_POOL);
    float* hbuf          = (float*)(wsb + O_H);
    float* wsm           = (float*)(wsb + O_WSM);
    float* out           = (float*)d_out;

    const unsigned short* Wqb  = WB + WO_WQ;
    const unsigned short* Wkb  = WB + WO_WK;
    const unsigned short* Wvb  = WB + WO_WV;
    const unsigned short* aiwb = WB + WO_AIW;
    const unsigned short* aowb = WB + WO_AOW;
    const unsigned short* cwb  = WB + WO_CW;
    const unsigned short* fw2b = WB + WO_FW2;

    // weight + input casts (cast_cw permutes conv weights to tap-major)
    cast_w<<<dim3(224), 256, 0, stream>>>(Wq, Wk, Wv, aiw, aow, fw2, WB);
    cast_cw<<<dim3(256), 256, 0, stream>>>(cw, (unsigned short*)(WB + WO_CW));
    cast_pool<<<dim3(S_*B_*C_), 256, 0, stream>>>(x, xb, pooled);
    imp1<<<dim3(C_), 256, 0, stream>>>(pooled, iw1, ib1, hbuf);
    imp2<<<dim3(1), 256, 0, stream>>>(hbuf, iw2, ib2, wsm);

    const dim3 g12(HW_/128, C_/128, S_*B_);
    const dim3 g4 (HW_/128, C_/128, B_);
    const dim3 gc (H_, C_/128, B_);

    // Q path
    mgemm<0><<<g12, 256, 0, stream>>>(xb, Wqb, bq, bnq, nullptr, s0b, 1);
    mgemm<1><<<g12, 256, 0, stream>>>(s0b, aiwb, aib, nullptr, nullptr, bufA, 0);
    // K path
    mgemm<0><<<g12, 256, 0, stream>>>(xb, Wkb, bk, bnk, nullptr, s0b, 1);
    mgemm<1><<<g12, 256, 0, stream>>>(s0b, aiwb + C_*C_, aib + C_, nullptr, nullptr, bufB, 0);
    // scores + softmax + importance-fold
    attn_scores<<<dim3(B_*HW_/256), 256, 0, stream>>>(bufA, bufB, wsm, aw_buf);
    // V path (VT overwrites bufA)
    mgemm<0><<<g12, 256, 0, stream>>>(xb, Wvb, bv, bnv, nullptr, s0b, 1);
    mgemm<1><<<g12, 256, 0, stream>>>(s0b, aiwb + 2*C_*C_, aib + 2*C_, nullptr, nullptr, bufA, 0);
    // OM = sum_t aw * VT
    om_combine<<<dim3(B_*CHW_/256), 256, 0, stream>>>(bufA, aw_buf, OMb);
    // attn-out projection (importance fold already applied)
    mgemm<1><<<g4, 256, 0, stream>>>(OMb, aowb, aob, nullptr, nullptr, INTb, 0);
    // 3x3 conv + bias + BN + gelu (tap-major flat-K MFMA)
    conv_mfma<<<gc, 256, 0, stream>>>(INTb, cwb, cb, cbn, CVb);
    // final 1x1 + bias + residual x[1] (fp32 out)
    mgemm<2><<<g4, 256, 0, stream>>>(CVb, fw2b, fb2, nullptr, x + (size_t)B_*CHW_, out, 0);
}